// Round 5
// baseline (613.925 us; speedup 1.0000x reference)
//
#include <hip/hip_runtime.h>
#include <hip/hip_bf16.h>
#include <math.h>

// Problem constants (from reference)
constexpr int N_ENT = 100000;
constexpr int NEDGE = 1600000;
constexpr int BATCH = 8192;
constexpr int NBLK_SCAN = (N_ENT + 255) / 256;   // 391

// ---------------------------------------------------------------------------
// Workspace layout (4-byte units):
//  degi      : [0, 100000)            int   degree counts
//  dinv      : [100000, 200000)       float 1/sqrt(deg+1)
//  scale     : [200000, 300000)       float renorm scale per entity
//  fsc       : [300000, 400000)       float scale*dinv per entity
//  row_start : [400000, 500001)       int   CSR offsets (100001)
//  cursor    : [500004, 600004)       int   placement cursors
//  partials  : [600004, 600404)       int   per-block degree sums (391)
//  srcs      : [600404, 2200404)      int   CSR src ids
//  z / h2    : [2200408, 8600408)     float [N,64] (z, then reused as h2)
//  y1r / z2  : [8600408, 21400408)    float [N,128] y1r, then z2 in first half
// Total ~85.6 MB.

// K1: degree histogram
__global__ __launch_bounds__(256) void deg_count(const int* __restrict__ edges,
                                                 int* __restrict__ degi) {
    int e = blockIdx.x * 256 + threadIdx.x;
    if (e < NEDGE) atomicAdd(&degi[edges[NEDGE + e]], 1);
}

// K2: per-entity renorm scale + dinv + fused factor — one wave per row
__global__ __launch_bounds__(256) void scale_k(const float* __restrict__ emb,
                                               const int* __restrict__ degi,
                                               float* __restrict__ dinv,
                                               float* __restrict__ scale,
                                               float* __restrict__ fsc) {
    int gt   = blockIdx.x * 256 + threadIdx.x;
    int n    = gt >> 6;
    int lane = threadIdx.x & 63;
    float v = emb[(size_t)n * 64 + lane];
    float s = v * v;
#pragma unroll
    for (int o = 32; o > 0; o >>= 1) s += __shfl_xor(s, o, 64);
    if (lane == 0) {
        float nrm = sqrtf(s);
        float sc  = nrm > 1.0f ? 1.0f / nrm : 1.0f;
        float dv  = 1.0f / sqrtf((float)(degi[n] + 1));
        scale[n] = sc;
        dinv[n]  = dv;
        fsc[n]   = sc * dv;
    }
}

// K3a: per-block degree sums
__global__ __launch_bounds__(256) void scan_partials(const int* __restrict__ degi,
                                                     int* __restrict__ partials) {
    __shared__ int ws[4];
    int i = blockIdx.x * 256 + threadIdx.x;
    int v = (i < N_ENT) ? degi[i] : 0;
#pragma unroll
    for (int o = 32; o > 0; o >>= 1) v += __shfl_xor(v, o, 64);
    if ((threadIdx.x & 63) == 0) ws[threadIdx.x >> 6] = v;
    __syncthreads();
    if (threadIdx.x == 0) partials[blockIdx.x] = ws[0] + ws[1] + ws[2] + ws[3];
}

// K3b: single small block — exclusive scan of 391 partials (in place)
__global__ __launch_bounds__(512) void scan_offsets(int* __restrict__ partials,
                                                    int* __restrict__ row_start) {
    __shared__ int ts[512];
    int t = threadIdx.x;
    int v = (t < NBLK_SCAN) ? partials[t] : 0;
    ts[t] = v;
    __syncthreads();
    for (int off = 1; off < 512; off <<= 1) {
        int x = (t >= off) ? ts[t - off] : 0;
        __syncthreads();
        ts[t] += x;
        __syncthreads();
    }
    if (t < NBLK_SCAN) partials[t] = ts[t] - v;
    if (t == 0) row_start[N_ENT] = NEDGE;
}

// K3c: per-block exclusive scan + block offset -> row_start, cursor
__global__ __launch_bounds__(256) void scan_apply(const int* __restrict__ degi,
                                                  const int* __restrict__ partials,
                                                  int* __restrict__ row_start,
                                                  int* __restrict__ cursor) {
    __shared__ int ts[256];
    int t = threadIdx.x;
    int i = blockIdx.x * 256 + t;
    int v = (i < N_ENT) ? degi[i] : 0;
    ts[t] = v;
    __syncthreads();
    for (int off = 1; off < 256; off <<= 1) {
        int x = (t >= off) ? ts[t - off] : 0;
        __syncthreads();
        ts[t] += x;
        __syncthreads();
    }
    if (i < N_ENT) {
        int excl = ts[t] - v + partials[blockIdx.x];
        row_start[i] = excl;
        cursor[i]    = excl;
    }
}

// K4: CSR placement — scattered write via atomicExch (payload-granular HBM
// traffic; plain 4B stores amplify 16x through 64B dirty-line evictions)
__global__ __launch_bounds__(256) void place_k(const int* __restrict__ edges,
                                               int* __restrict__ cursor,
                                               int* __restrict__ srcs) {
    int e = blockIdx.x * 256 + threadIdx.x;
    if (e >= NEDGE) return;
    int s = edges[e];
    int d = edges[NEDGE + e];
    int pos = atomicAdd(&cursor[d], 1);
    atomicExch(&srcs[pos], s);
}

// K5: layer-1 aggregate on RAW 64-dim input (scatter commuted before GEMM):
// z[d] = dinv[d] * sum_j fsc[s_j]*emb[s_j] + scale[d]*dinv[d]^2 * emb[d]
__global__ __launch_bounds__(256) void reduce1_k(const int* __restrict__ row_start,
                                                 const int* __restrict__ srcs,
                                                 const float* __restrict__ fsc,
                                                 const float* __restrict__ emb,
                                                 const float* __restrict__ dinv,
                                                 const float* __restrict__ scale,
                                                 float* __restrict__ z) {
    int gt   = blockIdx.x * 256 + threadIdx.x;
    int dst  = gt >> 6;
    int lane = threadIdx.x & 63;
    int beg = row_start[dst];
    int end = row_start[dst + 1];
    float acc0 = 0.f, acc1 = 0.f;
    for (int base = beg; base < end; base += 64) {
        int cnt = end - base; if (cnt > 64) cnt = 64;
        int   s_v = 0;
        float f_v = 0.f;
        if (base + lane < end) {
            s_v = srcs[base + lane];
            f_v = fsc[s_v];
        }
        int jj = 0;
        for (; jj + 1 < cnt; jj += 2) {
            int   s0 = __shfl(s_v, jj, 64), s1 = __shfl(s_v, jj + 1, 64);
            float f0 = __shfl(f_v, jj, 64), f1 = __shfl(f_v, jj + 1, 64);
            acc0 += f0 * emb[(size_t)s0 * 64 + lane];
            acc1 += f1 * emb[(size_t)s1 * 64 + lane];
        }
        if (jj < cnt) {
            int   s0 = __shfl(s_v, jj, 64);
            float f0 = __shfl(f_v, jj, 64);
            acc0 += f0 * emb[(size_t)s0 * 64 + lane];
        }
    }
    float dv   = dinv[dst];
    float self = scale[dst] * dv * dv;
    z[(size_t)dst * 64 + lane] = dv * (acc0 + acc1) + self * emb[(size_t)dst * 64 + lane];
}

// K6: y1r = relu(z @ W1 + b1)   [N,64]@[64,128]
__global__ __launch_bounds__(256) void gemm1_relu(const float* __restrict__ z,
                                                  const float* __restrict__ W1g,
                                                  const float* __restrict__ b1,
                                                  float* __restrict__ y1r) {
    __shared__ float W[64 * 128];
    __shared__ float A[16 * 65];     // +1 pad
    int tid = threadIdx.x;
    for (int idx = tid; idx < 64 * 128; idx += 256) W[idx] = W1g[idx];
    int row0 = blockIdx.x * 16;
    for (int idx = tid; idx < 16 * 64; idx += 256) {
        int r = idx >> 6, c = idx & 63;
        A[r * 65 + c] = z[(size_t)(row0 + r) * 64 + c];
    }
    __syncthreads();
    int c    = tid & 127;
    int half = tid >> 7;
    float acc[8];
#pragma unroll
    for (int r = 0; r < 8; ++r) acc[r] = 0.f;
    for (int k = 0; k < 64; ++k) {
        float w = W[k * 128 + c];
#pragma unroll
        for (int r = 0; r < 8; ++r) acc[r] += A[(half * 8 + r) * 65 + k] * w;
    }
    float bb = b1[c];
#pragma unroll
    for (int r = 0; r < 8; ++r) {
        float v = acc[r] + bb;
        y1r[(size_t)(row0 + half * 8 + r) * 128 + c] = v > 0.f ? v : 0.f;
    }
}

// K7: h2 = y1r @ W2   [N,128]@[128,64]
__global__ __launch_bounds__(256) void gemm2_k(const float* __restrict__ y1r,
                                               const float* __restrict__ W2g,
                                               float* __restrict__ h2) {
    __shared__ float W[128 * 64];
    __shared__ float A[16 * 129];    // +1 pad
    int tid = threadIdx.x;
    for (int idx = tid; idx < 128 * 64; idx += 256) W[idx] = W2g[idx];
    int row0 = blockIdx.x * 16;
    for (int idx = tid; idx < 16 * 128; idx += 256) {
        int r = idx >> 7, c = idx & 127;
        A[r * 129 + c] = y1r[(size_t)(row0 + r) * 128 + c];
    }
    __syncthreads();
    int c   = tid & 63;
    int grp = tid >> 6;
    float acc[4];
#pragma unroll
    for (int r = 0; r < 4; ++r) acc[r] = 0.f;
    for (int k = 0; k < 128; ++k) {
        float w = W[k * 64 + c];
#pragma unroll
        for (int r = 0; r < 4; ++r) acc[r] += A[(grp * 4 + r) * 129 + k] * w;
    }
#pragma unroll
    for (int r = 0; r < 4; ++r)
        h2[(size_t)(row0 + grp * 4 + r) * 64 + c] = acc[r];
}

// K8: layer-2 aggregate:
// z2[d] = dinv[d]*sum_j dinv[s_j]*h2[s_j] + dinv[d]^2*h2[d] + b2
__global__ __launch_bounds__(256) void reduce2_k(const int* __restrict__ row_start,
                                                 const int* __restrict__ srcs,
                                                 const float* __restrict__ dinv,
                                                 const float* __restrict__ h2,
                                                 const float* __restrict__ b2,
                                                 float* __restrict__ z2) {
    int gt   = blockIdx.x * 256 + threadIdx.x;
    int dst  = gt >> 6;
    int lane = threadIdx.x & 63;
    int beg = row_start[dst];
    int end = row_start[dst + 1];
    float acc0 = 0.f, acc1 = 0.f;
    for (int base = beg; base < end; base += 64) {
        int cnt = end - base; if (cnt > 64) cnt = 64;
        int   s_v = 0;
        float f_v = 0.f;
        if (base + lane < end) {
            s_v = srcs[base + lane];
            f_v = dinv[s_v];
        }
        int jj = 0;
        for (; jj + 1 < cnt; jj += 2) {
            int   s0 = __shfl(s_v, jj, 64), s1 = __shfl(s_v, jj + 1, 64);
            float f0 = __shfl(f_v, jj, 64), f1 = __shfl(f_v, jj + 1, 64);
            acc0 += f0 * h2[(size_t)s0 * 64 + lane];
            acc1 += f1 * h2[(size_t)s1 * 64 + lane];
        }
        if (jj < cnt) {
            int   s0 = __shfl(s_v, jj, 64);
            float f0 = __shfl(f_v, jj, 64);
            acc0 += f0 * h2[(size_t)s0 * 64 + lane];
        }
    }
    float dv = dinv[dst];
    z2[(size_t)dst * 64 + lane] =
        dv * (acc0 + acc1) + dv * dv * h2[(size_t)dst * 64 + lane] + b2[lane];
}

// K9: final — renorm(user)·item, sigmoid; one wave per batch element
__global__ __launch_bounds__(256) void final_dot(const int* __restrict__ u,
                                                 const int* __restrict__ iidx,
                                                 const float* __restrict__ uemb,
                                                 const float* __restrict__ z2,
                                                 float* __restrict__ out) {
    int gt   = blockIdx.x * 256 + threadIdx.x;
    int b    = gt >> 6;
    int lane = threadIdx.x & 63;
    int ui = u[b];
    int it = iidx[b];
    float ue = uemb[(size_t)ui * 64 + lane];
    float iv = z2[(size_t)it * 64 + lane];
    float s1 = ue * ue;
    float s2 = ue * iv;
#pragma unroll
    for (int o = 32; o > 0; o >>= 1) {
        s1 += __shfl_xor(s1, o, 64);
        s2 += __shfl_xor(s2, o, 64);
    }
    if (lane == 0) {
        float nrm = sqrtf(s1);
        float sc  = nrm > 1.0f ? 1.0f / nrm : 1.0f;
        float uv  = s2 * sc;
        out[b] = 1.0f / (1.0f + expf(-uv));
    }
}

// ---------------------------------------------------------------------------
extern "C" void kernel_launch(void* const* d_in, const int* in_sizes, int n_in,
                              void* d_out, int out_size, void* d_ws, size_t ws_size,
                              hipStream_t stream) {
    const int*   u          = (const int*)d_in[0];
    const int*   iidx       = (const int*)d_in[1];
    const int*   edges      = (const int*)d_in[2];
    const float* user_emb   = (const float*)d_in[3];
    const float* entity_emb = (const float*)d_in[4];
    const float* W1         = (const float*)d_in[5];
    const float* b1         = (const float*)d_in[6];
    const float* W2         = (const float*)d_in[7];
    const float* b2         = (const float*)d_in[8];
    float*       out        = (float*)d_out;

    char* ws = (char*)d_ws;
    int*   degi      = (int*)  (ws);
    float* dinv      = (float*)(ws + 100000u * 4);
    float* scale     = (float*)(ws + 200000u * 4);
    float* fsc       = (float*)(ws + 300000u * 4);
    int*   row_start = (int*)  (ws + 400000u * 4);
    int*   cursor    = (int*)  (ws + 500004u * 4);
    int*   partials  = (int*)  (ws + 600004u * 4);
    int*   srcs      = (int*)  (ws + 600404u * 4);
    float* z         = (float*)(ws + 2200408u * 4);   // reused as h2
    float* y1r       = (float*)(ws + 8600408u * 4);   // reused as z2
    float* h2 = z;
    float* z2 = y1r;

    hipMemsetAsync(degi, 0, N_ENT * sizeof(int), stream);
    deg_count<<<NEDGE / 256, 256, 0, stream>>>(edges, degi);
    scale_k<<<N_ENT * 64 / 256, 256, 0, stream>>>(entity_emb, degi, dinv, scale, fsc);

    scan_partials<<<NBLK_SCAN, 256, 0, stream>>>(degi, partials);
    scan_offsets<<<1, 512, 0, stream>>>(partials, row_start);
    scan_apply<<<NBLK_SCAN, 256, 0, stream>>>(degi, partials, row_start, cursor);

    place_k<<<NEDGE / 256, 256, 0, stream>>>(edges, cursor, srcs);

    reduce1_k<<<N_ENT * 64 / 256, 256, 0, stream>>>(row_start, srcs, fsc, entity_emb,
                                                    dinv, scale, z);
    gemm1_relu<<<N_ENT / 16, 256, 0, stream>>>(z, W1, b1, y1r);
    gemm2_k<<<N_ENT / 16, 256, 0, stream>>>(y1r, W2, h2);
    reduce2_k<<<N_ENT * 64 / 256, 256, 0, stream>>>(row_start, srcs, dinv, h2, b2, z2);

    final_dot<<<BATCH * 64 / 256, 256, 0, stream>>>(u, iidx, user_emb, z2, out);
}

// Round 6
// 516.622 us; speedup vs baseline: 1.1883x; 1.1883x over previous
//
#include <hip/hip_runtime.h>
#include <hip/hip_bf16.h>
#include <math.h>

// Problem constants (from reference)
constexpr int N_ENT = 100000;
constexpr int NEDGE = 1600000;
constexpr int BATCH = 8192;
constexpr int NBLK_SCAN = (N_ENT + 255) / 256;   // 391

// Bucketed CSR placement
constexpr int NBUCK = 256;                        // buckets of contiguous nodes
constexpr int KNODE = 391;                        // 256*391 = 100096 >= N_ENT
constexpr int TILE  = 4096;                       // edges per bin_k block
constexpr int NTILE = (NEDGE + TILE - 1) / TILE;  // 391

// ---------------------------------------------------------------------------
// Workspace layout (4-byte units):
//  degi      : [0, 100000)            int   degree counts
//  dinv      : [100000, 200000)       float 1/sqrt(deg+1)
//  scale     : [200000, 300000)       float renorm scale per entity
//  fsc       : [300000, 400000)       float scale*dinv per entity
//  row_start : [400000, 500001)       int   CSR offsets (100001)
//  gcursor   : [500004, 500260)       int   per-bucket placement cursors (256)
//  partials  : [500264, 500655)       int   per-block degree sums (391)
//  srcs      : [500656, 2100656)      int   CSR src ids
//  temp      : [2100656, 3700656)     uint  bucketed packed (src<<9|dstLocal)
//  z / h2    : [3700656, 10100656)    float [N,64] (z, then reused as h2)
//  y1r / z2  : [10100656, 22900656)   float [N,128] y1r, then z2 in first half
// Total ~91.6 MB.

// K1: degree histogram
__global__ __launch_bounds__(256) void deg_count(const int* __restrict__ edges,
                                                 int* __restrict__ degi) {
    int e = blockIdx.x * 256 + threadIdx.x;
    if (e < NEDGE) atomicAdd(&degi[edges[NEDGE + e]], 1);
}

// K2: per-entity renorm scale + dinv + fused factor — one wave per row
__global__ __launch_bounds__(256) void scale_k(const float* __restrict__ emb,
                                               const int* __restrict__ degi,
                                               float* __restrict__ dinv,
                                               float* __restrict__ scale,
                                               float* __restrict__ fsc) {
    int gt   = blockIdx.x * 256 + threadIdx.x;
    int n    = gt >> 6;
    int lane = threadIdx.x & 63;
    float v = emb[(size_t)n * 64 + lane];
    float s = v * v;
#pragma unroll
    for (int o = 32; o > 0; o >>= 1) s += __shfl_xor(s, o, 64);
    if (lane == 0) {
        float nrm = sqrtf(s);
        float sc  = nrm > 1.0f ? 1.0f / nrm : 1.0f;
        float dv  = 1.0f / sqrtf((float)(degi[n] + 1));
        scale[n] = sc;
        dinv[n]  = dv;
        fsc[n]   = sc * dv;
    }
}

// K3a: per-block degree sums
__global__ __launch_bounds__(256) void scan_partials(const int* __restrict__ degi,
                                                     int* __restrict__ partials) {
    __shared__ int ws[4];
    int i = blockIdx.x * 256 + threadIdx.x;
    int v = (i < N_ENT) ? degi[i] : 0;
#pragma unroll
    for (int o = 32; o > 0; o >>= 1) v += __shfl_xor(v, o, 64);
    if ((threadIdx.x & 63) == 0) ws[threadIdx.x >> 6] = v;
    __syncthreads();
    if (threadIdx.x == 0) partials[blockIdx.x] = ws[0] + ws[1] + ws[2] + ws[3];
}

// K3b: single small block — exclusive scan of 391 partials (in place)
__global__ __launch_bounds__(512) void scan_offsets(int* __restrict__ partials,
                                                    int* __restrict__ row_start) {
    __shared__ int ts[512];
    int t = threadIdx.x;
    int v = (t < NBLK_SCAN) ? partials[t] : 0;
    ts[t] = v;
    __syncthreads();
    for (int off = 1; off < 512; off <<= 1) {
        int x = (t >= off) ? ts[t - off] : 0;
        __syncthreads();
        ts[t] += x;
        __syncthreads();
    }
    if (t < NBLK_SCAN) partials[t] = ts[t] - v;
    if (t == 0) row_start[N_ENT] = NEDGE;
}

// K3c: per-block exclusive scan + block offset -> row_start
__global__ __launch_bounds__(256) void scan_apply(const int* __restrict__ degi,
                                                  const int* __restrict__ partials,
                                                  int* __restrict__ row_start) {
    __shared__ int ts[256];
    int t = threadIdx.x;
    int i = blockIdx.x * 256 + t;
    int v = (i < N_ENT) ? degi[i] : 0;
    ts[t] = v;
    __syncthreads();
    for (int off = 1; off < 256; off <<= 1) {
        int x = (t >= off) ? ts[t - off] : 0;
        __syncthreads();
        ts[t] += x;
        __syncthreads();
    }
    if (i < N_ENT) row_start[i] = ts[t] - v + partials[blockIdx.x];
}

// K3d: per-bucket cursor init — gcursor[b] = row_start[b*KNODE]
__global__ __launch_bounds__(256) void binit_k(const int* __restrict__ row_start,
                                               int* __restrict__ gcursor) {
    int b = threadIdx.x;   // one block of 256
    gcursor[b] = row_start[b * KNODE];
}

// K4a: bucket binning — per 4096-edge tile, group writes by 256 node-buckets.
// Writes form contiguous per-(tile,bucket) runs -> dirtied L2 lines are fully
// covered -> payload-granular HBM writeback (the R5 lesson: it's line
// coverage, not atomic-vs-store, that controls write amplification).
__global__ __launch_bounds__(256) void bin_k(const int* __restrict__ edges,
                                             int* __restrict__ gcursor,
                                             unsigned int* __restrict__ temp) {
    __shared__ int cnt[NBUCK];
    __shared__ int gb[NBUCK];
    __shared__ int off[NBUCK];
    int tid  = threadIdx.x;
    int base = blockIdx.x * TILE;
    int sv[16], dv[16], bv[16];
    cnt[tid] = 0;
    __syncthreads();
#pragma unroll
    for (int i = 0; i < 16; ++i) {
        int e = base + i * 256 + tid;
        if (e < NEDGE) {
            sv[i] = edges[e];
            dv[i] = edges[NEDGE + e];
            bv[i] = dv[i] / KNODE;
            atomicAdd(&cnt[bv[i]], 1);
        } else {
            bv[i] = -1;
        }
    }
    __syncthreads();
    if (cnt[tid] > 0) gb[tid] = atomicAdd(&gcursor[tid], cnt[tid]);
    off[tid] = 0;
    __syncthreads();
#pragma unroll
    for (int i = 0; i < 16; ++i) {
        int b = bv[i];
        if (b >= 0) {
            int p  = atomicAdd(&off[b], 1);
            int dl = dv[i] - b * KNODE;
            temp[gb[b] + p] = ((unsigned int)sv[i] << 9) | (unsigned int)dl;
        }
    }
}

// K4b: within-bucket placement — one block per bucket; LDS per-node cursors;
// scattered 4B writes stay inside the block's own contiguous region (fully
// covered collectively -> payload-granular writeback).
__global__ __launch_bounds__(256) void unbin_k(const unsigned int* __restrict__ temp,
                                               const int* __restrict__ row_start,
                                               int* __restrict__ srcs) {
    __shared__ int cur[KNODE];
    int b     = blockIdx.x;
    int node0 = b * KNODE;
    int nn    = N_ENT - node0; if (nn > KNODE) nn = KNODE;
    for (int i = threadIdx.x; i < nn; i += 256) cur[i] = row_start[node0 + i];
    __syncthreads();
    int rbeg = row_start[node0];
    int rend = row_start[node0 + nn];
    for (int idx = rbeg + threadIdx.x; idx < rend; idx += 256) {
        unsigned int v = temp[idx];
        int dl = (int)(v & 511u);
        int s  = (int)(v >> 9);
        int pos = atomicAdd(&cur[dl], 1);
        srcs[pos] = s;
    }
}

// K5: layer-1 aggregate on RAW 64-dim input (scatter commuted before GEMM):
// z[d] = dinv[d] * sum_j fsc[s_j]*emb[s_j] + scale[d]*dinv[d]^2 * emb[d]
__global__ __launch_bounds__(256) void reduce1_k(const int* __restrict__ row_start,
                                                 const int* __restrict__ srcs,
                                                 const float* __restrict__ fsc,
                                                 const float* __restrict__ emb,
                                                 const float* __restrict__ dinv,
                                                 const float* __restrict__ scale,
                                                 float* __restrict__ z) {
    int gt   = blockIdx.x * 256 + threadIdx.x;
    int dst  = gt >> 6;
    int lane = threadIdx.x & 63;
    int beg = row_start[dst];
    int end = row_start[dst + 1];
    float acc0 = 0.f, acc1 = 0.f;
    for (int base = beg; base < end; base += 64) {
        int cnt = end - base; if (cnt > 64) cnt = 64;
        int   s_v = 0;
        float f_v = 0.f;
        if (base + lane < end) {
            s_v = srcs[base + lane];
            f_v = fsc[s_v];
        }
        int jj = 0;
        for (; jj + 1 < cnt; jj += 2) {
            int   s0 = __shfl(s_v, jj, 64), s1 = __shfl(s_v, jj + 1, 64);
            float f0 = __shfl(f_v, jj, 64), f1 = __shfl(f_v, jj + 1, 64);
            acc0 += f0 * emb[(size_t)s0 * 64 + lane];
            acc1 += f1 * emb[(size_t)s1 * 64 + lane];
        }
        if (jj < cnt) {
            int   s0 = __shfl(s_v, jj, 64);
            float f0 = __shfl(f_v, jj, 64);
            acc0 += f0 * emb[(size_t)s0 * 64 + lane];
        }
    }
    float dv   = dinv[dst];
    float self = scale[dst] * dv * dv;
    z[(size_t)dst * 64 + lane] = dv * (acc0 + acc1) + self * emb[(size_t)dst * 64 + lane];
}

// K6: y1r = relu(z @ W1 + b1)   [N,64]@[64,128]
__global__ __launch_bounds__(256) void gemm1_relu(const float* __restrict__ z,
                                                  const float* __restrict__ W1g,
                                                  const float* __restrict__ b1,
                                                  float* __restrict__ y1r) {
    __shared__ float W[64 * 128];
    __shared__ float A[16 * 65];     // +1 pad
    int tid = threadIdx.x;
    for (int idx = tid; idx < 64 * 128; idx += 256) W[idx] = W1g[idx];
    int row0 = blockIdx.x * 16;
    for (int idx = tid; idx < 16 * 64; idx += 256) {
        int r = idx >> 6, c = idx & 63;
        A[r * 65 + c] = z[(size_t)(row0 + r) * 64 + c];
    }
    __syncthreads();
    int c    = tid & 127;
    int half = tid >> 7;
    float acc[8];
#pragma unroll
    for (int r = 0; r < 8; ++r) acc[r] = 0.f;
    for (int k = 0; k < 64; ++k) {
        float w = W[k * 128 + c];
#pragma unroll
        for (int r = 0; r < 8; ++r) acc[r] += A[(half * 8 + r) * 65 + k] * w;
    }
    float bb = b1[c];
#pragma unroll
    for (int r = 0; r < 8; ++r) {
        float v = acc[r] + bb;
        y1r[(size_t)(row0 + half * 8 + r) * 128 + c] = v > 0.f ? v : 0.f;
    }
}

// K7: h2 = y1r @ W2   [N,128]@[128,64]
__global__ __launch_bounds__(256) void gemm2_k(const float* __restrict__ y1r,
                                               const float* __restrict__ W2g,
                                               float* __restrict__ h2) {
    __shared__ float W[128 * 64];
    __shared__ float A[16 * 129];    // +1 pad
    int tid = threadIdx.x;
    for (int idx = tid; idx < 128 * 64; idx += 256) W[idx] = W2g[idx];
    int row0 = blockIdx.x * 16;
    for (int idx = tid; idx < 16 * 128; idx += 256) {
        int r = idx >> 7, c = idx & 127;
        A[r * 129 + c] = y1r[(size_t)(row0 + r) * 128 + c];
    }
    __syncthreads();
    int c   = tid & 63;
    int grp = tid >> 6;
    float acc[4];
#pragma unroll
    for (int r = 0; r < 4; ++r) acc[r] = 0.f;
    for (int k = 0; k < 128; ++k) {
        float w = W[k * 64 + c];
#pragma unroll
        for (int r = 0; r < 4; ++r) acc[r] += A[(grp * 4 + r) * 129 + k] * w;
    }
#pragma unroll
    for (int r = 0; r < 4; ++r)
        h2[(size_t)(row0 + grp * 4 + r) * 64 + c] = acc[r];
}

// K8: layer-2 aggregate:
// z2[d] = dinv[d]*sum_j dinv[s_j]*h2[s_j] + dinv[d]^2*h2[d] + b2
__global__ __launch_bounds__(256) void reduce2_k(const int* __restrict__ row_start,
                                                 const int* __restrict__ srcs,
                                                 const float* __restrict__ dinv,
                                                 const float* __restrict__ h2,
                                                 const float* __restrict__ b2,
                                                 float* __restrict__ z2) {
    int gt   = blockIdx.x * 256 + threadIdx.x;
    int dst  = gt >> 6;
    int lane = threadIdx.x & 63;
    int beg = row_start[dst];
    int end = row_start[dst + 1];
    float acc0 = 0.f, acc1 = 0.f;
    for (int base = beg; base < end; base += 64) {
        int cnt = end - base; if (cnt > 64) cnt = 64;
        int   s_v = 0;
        float f_v = 0.f;
        if (base + lane < end) {
            s_v = srcs[base + lane];
            f_v = dinv[s_v];
        }
        int jj = 0;
        for (; jj + 1 < cnt; jj += 2) {
            int   s0 = __shfl(s_v, jj, 64), s1 = __shfl(s_v, jj + 1, 64);
            float f0 = __shfl(f_v, jj, 64), f1 = __shfl(f_v, jj + 1, 64);
            acc0 += f0 * h2[(size_t)s0 * 64 + lane];
            acc1 += f1 * h2[(size_t)s1 * 64 + lane];
        }
        if (jj < cnt) {
            int   s0 = __shfl(s_v, jj, 64);
            float f0 = __shfl(f_v, jj, 64);
            acc0 += f0 * h2[(size_t)s0 * 64 + lane];
        }
    }
    float dv = dinv[dst];
    z2[(size_t)dst * 64 + lane] =
        dv * (acc0 + acc1) + dv * dv * h2[(size_t)dst * 64 + lane] + b2[lane];
}

// K9: final — renorm(user)·item, sigmoid; one wave per batch element
__global__ __launch_bounds__(256) void final_dot(const int* __restrict__ u,
                                                 const int* __restrict__ iidx,
                                                 const float* __restrict__ uemb,
                                                 const float* __restrict__ z2,
                                                 float* __restrict__ out) {
    int gt   = blockIdx.x * 256 + threadIdx.x;
    int b    = gt >> 6;
    int lane = threadIdx.x & 63;
    int ui = u[b];
    int it = iidx[b];
    float ue = uemb[(size_t)ui * 64 + lane];
    float iv = z2[(size_t)it * 64 + lane];
    float s1 = ue * ue;
    float s2 = ue * iv;
#pragma unroll
    for (int o = 32; o > 0; o >>= 1) {
        s1 += __shfl_xor(s1, o, 64);
        s2 += __shfl_xor(s2, o, 64);
    }
    if (lane == 0) {
        float nrm = sqrtf(s1);
        float sc  = nrm > 1.0f ? 1.0f / nrm : 1.0f;
        float uv  = s2 * sc;
        out[b] = 1.0f / (1.0f + expf(-uv));
    }
}

// ---------------------------------------------------------------------------
extern "C" void kernel_launch(void* const* d_in, const int* in_sizes, int n_in,
                              void* d_out, int out_size, void* d_ws, size_t ws_size,
                              hipStream_t stream) {
    const int*   u          = (const int*)d_in[0];
    const int*   iidx       = (const int*)d_in[1];
    const int*   edges      = (const int*)d_in[2];
    const float* user_emb   = (const float*)d_in[3];
    const float* entity_emb = (const float*)d_in[4];
    const float* W1         = (const float*)d_in[5];
    const float* b1         = (const float*)d_in[6];
    const float* W2         = (const float*)d_in[7];
    const float* b2         = (const float*)d_in[8];
    float*       out        = (float*)d_out;

    char* ws = (char*)d_ws;
    int*          degi      = (int*)          (ws);
    float*        dinv      = (float*)        (ws + 100000u * 4);
    float*        scale     = (float*)        (ws + 200000u * 4);
    float*        fsc       = (float*)        (ws + 300000u * 4);
    int*          row_start = (int*)          (ws + 400000u * 4);
    int*          gcursor   = (int*)          (ws + 500004u * 4);
    int*          partials  = (int*)          (ws + 500264u * 4);
    int*          srcs      = (int*)          (ws + 500656u * 4);
    unsigned int* temp      = (unsigned int*) (ws + 2100656u * 4);
    float*        z         = (float*)        (ws + 3700656u * 4);   // reused as h2
    float*        y1r       = (float*)        (ws + 10100656u * 4);  // reused as z2
    float* h2 = z;
    float* z2 = y1r;

    hipMemsetAsync(degi, 0, N_ENT * sizeof(int), stream);
    deg_count<<<NEDGE / 256, 256, 0, stream>>>(edges, degi);
    scale_k<<<N_ENT * 64 / 256, 256, 0, stream>>>(entity_emb, degi, dinv, scale, fsc);

    scan_partials<<<NBLK_SCAN, 256, 0, stream>>>(degi, partials);
    scan_offsets<<<1, 512, 0, stream>>>(partials, row_start);
    scan_apply<<<NBLK_SCAN, 256, 0, stream>>>(degi, partials, row_start);
    binit_k<<<1, 256, 0, stream>>>(row_start, gcursor);

    bin_k<<<NTILE, 256, 0, stream>>>(edges, gcursor, temp);
    unbin_k<<<NBUCK, 256, 0, stream>>>(temp, row_start, srcs);

    reduce1_k<<<N_ENT * 64 / 256, 256, 0, stream>>>(row_start, srcs, fsc, entity_emb,
                                                    dinv, scale, z);
    gemm1_relu<<<N_ENT / 16, 256, 0, stream>>>(z, W1, b1, y1r);
    gemm2_k<<<N_ENT / 16, 256, 0, stream>>>(y1r, W2, h2);
    reduce2_k<<<N_ENT * 64 / 256, 256, 0, stream>>>(row_start, srcs, dinv, h2, b2, z2);

    final_dot<<<BATCH * 64 / 256, 256, 0, stream>>>(u, iidx, user_emb, z2, out);
}

// Round 7
// 470.144 us; speedup vs baseline: 1.3058x; 1.0989x over previous
//
#include <hip/hip_runtime.h>
#include <hip/hip_bf16.h>
#include <math.h>

// Problem constants (from reference)
constexpr int N_ENT = 100000;
constexpr int NEDGE = 1600000;
constexpr int BATCH = 8192;
constexpr int NBLK_SCAN = (N_ENT + 255) / 256;   // 391

// Bucketed CSR placement
constexpr int NBUCK = 256;
constexpr int KNODE = 391;                        // 256*391 >= N_ENT
constexpr int TILE  = 4096;
constexpr int NTILE = (NEDGE + TILE - 1) / TILE;  // 391

// bf16 helpers (RNE pack, exact unpack)
__device__ inline unsigned short f2b(float x) {
    unsigned int u = __float_as_uint(x);
    unsigned int r = (u + 0x7fffu + ((u >> 16) & 1u)) >> 16;
    return (unsigned short)r;
}
__device__ inline float b2f(unsigned short h) {
    return __uint_as_float(((unsigned int)h) << 16);
}

// ---------------------------------------------------------------------------
// Workspace layout (4-byte units):
//  degi      : [0, 100000)             int
//  dinv      : [100000, 200000)        float
//  row_start : [200000, 300001)        int (100001)
//  gcursor   : [300004, 300260)        int (256)
//  partials  : [300264, 300655)        int (391)
//  srcs      : [300656, 1900656)       int CSR src ids
//  temp      : [1900656, 3500656)      uint packed (src<<9|dstLocal)
//  emb_b     : [3500656, 6700656)      ushort[N*64] premult bf16 entity rows
//  z / h2b   : [6700656, 13100656)     float [N,64] z; h2b (ushort[N*64]) reuses
//  y1r / z2  : [13100656, 25900656)    float [N,128] y1r, then z2 in first half
// Total ~103.6 MB (R1 ran with 102.8 MB).

// K1: degree histogram
__global__ __launch_bounds__(256) void deg_count(const int* __restrict__ edges,
                                                 int* __restrict__ degi) {
    int e = blockIdx.x * 256 + threadIdx.x;
    if (e < NEDGE) atomicAdd(&degi[edges[NEDGE + e]], 1);
}

// K2: prep — dinv + premultiplied bf16 entity rows
// emb_b[n] = bf16(scale[n]*dinv[n]*emb[n]); layer-1 factors fully folded.
__global__ __launch_bounds__(256) void prep_k(const float* __restrict__ emb,
                                              const int* __restrict__ degi,
                                              float* __restrict__ dinv,
                                              unsigned short* __restrict__ emb_b) {
    int gt   = blockIdx.x * 256 + threadIdx.x;
    int n    = gt >> 6;
    int lane = threadIdx.x & 63;
    float v = emb[(size_t)n * 64 + lane];
    float s = v * v;
#pragma unroll
    for (int o = 32; o > 0; o >>= 1) s += __shfl_xor(s, o, 64);  // all lanes get sum
    float nrm = sqrtf(s);
    float sc  = nrm > 1.0f ? 1.0f / nrm : 1.0f;
    float dv  = 1.0f / sqrtf((float)(degi[n] + 1));
    if (lane == 0) dinv[n] = dv;
    emb_b[(size_t)n * 64 + lane] = f2b(sc * dv * v);
}

// K3a: per-block degree sums
__global__ __launch_bounds__(256) void scan_partials(const int* __restrict__ degi,
                                                     int* __restrict__ partials) {
    __shared__ int ws[4];
    int i = blockIdx.x * 256 + threadIdx.x;
    int v = (i < N_ENT) ? degi[i] : 0;
#pragma unroll
    for (int o = 32; o > 0; o >>= 1) v += __shfl_xor(v, o, 64);
    if ((threadIdx.x & 63) == 0) ws[threadIdx.x >> 6] = v;
    __syncthreads();
    if (threadIdx.x == 0) partials[blockIdx.x] = ws[0] + ws[1] + ws[2] + ws[3];
}

// K3b: exclusive scan of 391 partials
__global__ __launch_bounds__(512) void scan_offsets(int* __restrict__ partials,
                                                    int* __restrict__ row_start) {
    __shared__ int ts[512];
    int t = threadIdx.x;
    int v = (t < NBLK_SCAN) ? partials[t] : 0;
    ts[t] = v;
    __syncthreads();
    for (int off = 1; off < 512; off <<= 1) {
        int x = (t >= off) ? ts[t - off] : 0;
        __syncthreads();
        ts[t] += x;
        __syncthreads();
    }
    if (t < NBLK_SCAN) partials[t] = ts[t] - v;
    if (t == 0) row_start[N_ENT] = NEDGE;
}

// K3c: per-block exclusive scan + offset -> row_start
__global__ __launch_bounds__(256) void scan_apply(const int* __restrict__ degi,
                                                  const int* __restrict__ partials,
                                                  int* __restrict__ row_start) {
    __shared__ int ts[256];
    int t = threadIdx.x;
    int i = blockIdx.x * 256 + t;
    int v = (i < N_ENT) ? degi[i] : 0;
    ts[t] = v;
    __syncthreads();
    for (int off = 1; off < 256; off <<= 1) {
        int x = (t >= off) ? ts[t - off] : 0;
        __syncthreads();
        ts[t] += x;
        __syncthreads();
    }
    if (i < N_ENT) row_start[i] = ts[t] - v + partials[blockIdx.x];
}

// K3d: per-bucket cursor init
__global__ __launch_bounds__(256) void binit_k(const int* __restrict__ row_start,
                                               int* __restrict__ gcursor) {
    gcursor[threadIdx.x] = row_start[threadIdx.x * KNODE];
}

// K4a: bucket binning (contiguous per-(tile,bucket) runs -> covered lines)
__global__ __launch_bounds__(256) void bin_k(const int* __restrict__ edges,
                                             int* __restrict__ gcursor,
                                             unsigned int* __restrict__ temp) {
    __shared__ int cnt[NBUCK];
    __shared__ int gb[NBUCK];
    __shared__ int off[NBUCK];
    int tid  = threadIdx.x;
    int base = blockIdx.x * TILE;
    int sv[16], dv[16], bv[16];
    cnt[tid] = 0;
    __syncthreads();
#pragma unroll
    for (int i = 0; i < 16; ++i) {
        int e = base + i * 256 + tid;
        if (e < NEDGE) {
            sv[i] = edges[e];
            dv[i] = edges[NEDGE + e];
            bv[i] = dv[i] / KNODE;
            atomicAdd(&cnt[bv[i]], 1);
        } else {
            bv[i] = -1;
        }
    }
    __syncthreads();
    if (cnt[tid] > 0) gb[tid] = atomicAdd(&gcursor[tid], cnt[tid]);
    off[tid] = 0;
    __syncthreads();
#pragma unroll
    for (int i = 0; i < 16; ++i) {
        int b = bv[i];
        if (b >= 0) {
            int p  = atomicAdd(&off[b], 1);
            int dl = dv[i] - b * KNODE;
            temp[gb[b] + p] = ((unsigned int)sv[i] << 9) | (unsigned int)dl;
        }
    }
}

// K4b: within-bucket placement (writes confined to contiguous region)
__global__ __launch_bounds__(256) void unbin_k(const unsigned int* __restrict__ temp,
                                               const int* __restrict__ row_start,
                                               int* __restrict__ srcs) {
    __shared__ int cur[KNODE];
    int b     = blockIdx.x;
    int node0 = b * KNODE;
    int nn    = N_ENT - node0; if (nn > KNODE) nn = KNODE;
    for (int i = threadIdx.x; i < nn; i += 256) cur[i] = row_start[node0 + i];
    __syncthreads();
    int rbeg = row_start[node0];
    int rend = row_start[node0 + nn];
    for (int idx = rbeg + threadIdx.x; idx < rend; idx += 256) {
        unsigned int v = temp[idx];
        int dl = (int)(v & 511u);
        int s  = (int)(v >> 9);
        int pos = atomicAdd(&cur[dl], 1);
        srcs[pos] = s;
    }
}

// K5: layer-1 aggregate: z[d] = dinv[d] * (sum_j emb_b[s_j] + emb_b[d])
// (all renorm/norm factors pre-folded into the bf16 rows)
__global__ __launch_bounds__(256) void reduce1_k(const int* __restrict__ row_start,
                                                 const int* __restrict__ srcs,
                                                 const unsigned short* __restrict__ emb_b,
                                                 const float* __restrict__ dinv,
                                                 float* __restrict__ z) {
    int gt   = blockIdx.x * 256 + threadIdx.x;
    int dst  = gt >> 6;
    int lane = threadIdx.x & 63;
    int beg = row_start[dst];
    int end = row_start[dst + 1];
    float a0 = 0.f, a1 = 0.f, a2 = 0.f, a3 = 0.f;
    for (int base = beg; base < end; base += 64) {
        int cnt = end - base; if (cnt > 64) cnt = 64;
        int s_v = (base + lane < end) ? srcs[base + lane] : 0;
        int jj = 0;
        for (; jj + 3 < cnt; jj += 4) {
            int s0 = __shfl(s_v, jj, 64),     s1 = __shfl(s_v, jj + 1, 64);
            int s2 = __shfl(s_v, jj + 2, 64), s3 = __shfl(s_v, jj + 3, 64);
            a0 += b2f(emb_b[(size_t)s0 * 64 + lane]);
            a1 += b2f(emb_b[(size_t)s1 * 64 + lane]);
            a2 += b2f(emb_b[(size_t)s2 * 64 + lane]);
            a3 += b2f(emb_b[(size_t)s3 * 64 + lane]);
        }
        for (; jj < cnt; ++jj) {
            int s0 = __shfl(s_v, jj, 64);
            a0 += b2f(emb_b[(size_t)s0 * 64 + lane]);
        }
    }
    float own = b2f(emb_b[(size_t)dst * 64 + lane]);
    z[(size_t)dst * 64 + lane] = dinv[dst] * (a0 + a1 + a2 + a3 + own);
}

// K6: y1r = relu(z @ W1 + b1)   [N,64]@[64,128]
__global__ __launch_bounds__(256) void gemm1_relu(const float* __restrict__ z,
                                                  const float* __restrict__ W1g,
                                                  const float* __restrict__ b1,
                                                  float* __restrict__ y1r) {
    __shared__ float W[64 * 128];
    __shared__ float A[16 * 65];     // +1 pad
    int tid = threadIdx.x;
    for (int idx = tid; idx < 64 * 128; idx += 256) W[idx] = W1g[idx];
    int row0 = blockIdx.x * 16;
    for (int idx = tid; idx < 16 * 64; idx += 256) {
        int r = idx >> 6, c = idx & 63;
        A[r * 65 + c] = z[(size_t)(row0 + r) * 64 + c];
    }
    __syncthreads();
    int c    = tid & 127;
    int half = tid >> 7;
    float acc[8];
#pragma unroll
    for (int r = 0; r < 8; ++r) acc[r] = 0.f;
    for (int k = 0; k < 64; ++k) {
        float w = W[k * 128 + c];
#pragma unroll
        for (int r = 0; r < 8; ++r) acc[r] += A[(half * 8 + r) * 65 + k] * w;
    }
    float bb = b1[c];
#pragma unroll
    for (int r = 0; r < 8; ++r) {
        float v = acc[r] + bb;
        y1r[(size_t)(row0 + half * 8 + r) * 128 + c] = v > 0.f ? v : 0.f;
    }
}

// K7: h2b = bf16(dinv[row] * (y1r @ W2))   [N,128]@[128,64] -> bf16 rows
// (layer-2 src factor folded into the row; self term becomes "add own row")
__global__ __launch_bounds__(256) void gemm2_k(const float* __restrict__ y1r,
                                               const float* __restrict__ W2g,
                                               const float* __restrict__ dinv,
                                               unsigned short* __restrict__ h2b) {
    __shared__ float W[128 * 64];
    __shared__ float A[16 * 129];    // +1 pad
    int tid = threadIdx.x;
    for (int idx = tid; idx < 128 * 64; idx += 256) W[idx] = W2g[idx];
    int row0 = blockIdx.x * 16;
    for (int idx = tid; idx < 16 * 128; idx += 256) {
        int r = idx >> 7, c = idx & 127;
        A[r * 129 + c] = y1r[(size_t)(row0 + r) * 128 + c];
    }
    __syncthreads();
    int c   = tid & 63;
    int grp = tid >> 6;
    float acc[4];
#pragma unroll
    for (int r = 0; r < 4; ++r) acc[r] = 0.f;
    for (int k = 0; k < 128; ++k) {
        float w = W[k * 64 + c];
#pragma unroll
        for (int r = 0; r < 4; ++r) acc[r] += A[(grp * 4 + r) * 129 + k] * w;
    }
#pragma unroll
    for (int r = 0; r < 4; ++r) {
        int row = row0 + grp * 4 + r;
        h2b[(size_t)row * 64 + c] = f2b(acc[r] * dinv[row]);
    }
}

// K8: layer-2 aggregate: z2[d] = dinv[d]*(sum_j h2b[s_j] + h2b[d]) + b2
__global__ __launch_bounds__(256) void reduce2_k(const int* __restrict__ row_start,
                                                 const int* __restrict__ srcs,
                                                 const unsigned short* __restrict__ h2b,
                                                 const float* __restrict__ dinv,
                                                 const float* __restrict__ b2,
                                                 float* __restrict__ z2) {
    int gt   = blockIdx.x * 256 + threadIdx.x;
    int dst  = gt >> 6;
    int lane = threadIdx.x & 63;
    int beg = row_start[dst];
    int end = row_start[dst + 1];
    float a0 = 0.f, a1 = 0.f, a2 = 0.f, a3 = 0.f;
    for (int base = beg; base < end; base += 64) {
        int cnt = end - base; if (cnt > 64) cnt = 64;
        int s_v = (base + lane < end) ? srcs[base + lane] : 0;
        int jj = 0;
        for (; jj + 3 < cnt; jj += 4) {
            int s0 = __shfl(s_v, jj, 64),     s1 = __shfl(s_v, jj + 1, 64);
            int s2 = __shfl(s_v, jj + 2, 64), s3 = __shfl(s_v, jj + 3, 64);
            a0 += b2f(h2b[(size_t)s0 * 64 + lane]);
            a1 += b2f(h2b[(size_t)s1 * 64 + lane]);
            a2 += b2f(h2b[(size_t)s2 * 64 + lane]);
            a3 += b2f(h2b[(size_t)s3 * 64 + lane]);
        }
        for (; jj < cnt; ++jj) {
            int s0 = __shfl(s_v, jj, 64);
            a0 += b2f(h2b[(size_t)s0 * 64 + lane]);
        }
    }
    float own = b2f(h2b[(size_t)dst * 64 + lane]);
    z2[(size_t)dst * 64 + lane] =
        dinv[dst] * (a0 + a1 + a2 + a3 + own) + b2[lane];
}

// K9: final — renorm(user)·item, sigmoid; one wave per batch element
__global__ __launch_bounds__(256) void final_dot(const int* __restrict__ u,
                                                 const int* __restrict__ iidx,
                                                 const float* __restrict__ uemb,
                                                 const float* __restrict__ z2,
                                                 float* __restrict__ out) {
    int gt   = blockIdx.x * 256 + threadIdx.x;
    int b    = gt >> 6;
    int lane = threadIdx.x & 63;
    int ui = u[b];
    int it = iidx[b];
    float ue = uemb[(size_t)ui * 64 + lane];
    float iv = z2[(size_t)it * 64 + lane];
    float s1 = ue * ue;
    float s2 = ue * iv;
#pragma unroll
    for (int o = 32; o > 0; o >>= 1) {
        s1 += __shfl_xor(s1, o, 64);
        s2 += __shfl_xor(s2, o, 64);
    }
    if (lane == 0) {
        float nrm = sqrtf(s1);
        float sc  = nrm > 1.0f ? 1.0f / nrm : 1.0f;
        float uv  = s2 * sc;
        out[b] = 1.0f / (1.0f + expf(-uv));
    }
}

// ---------------------------------------------------------------------------
extern "C" void kernel_launch(void* const* d_in, const int* in_sizes, int n_in,
                              void* d_out, int out_size, void* d_ws, size_t ws_size,
                              hipStream_t stream) {
    const int*   u          = (const int*)d_in[0];
    const int*   iidx       = (const int*)d_in[1];
    const int*   edges      = (const int*)d_in[2];
    const float* user_emb   = (const float*)d_in[3];
    const float* entity_emb = (const float*)d_in[4];
    const float* W1         = (const float*)d_in[5];
    const float* b1         = (const float*)d_in[6];
    const float* W2         = (const float*)d_in[7];
    const float* b2         = (const float*)d_in[8];
    float*       out        = (float*)d_out;

    char* ws = (char*)d_ws;
    int*            degi      = (int*)           (ws);
    float*          dinv      = (float*)         (ws + 100000u * 4);
    int*            row_start = (int*)           (ws + 200000u * 4);
    int*            gcursor   = (int*)           (ws + 300004u * 4);
    int*            partials  = (int*)           (ws + 300264u * 4);
    int*            srcs      = (int*)           (ws + 300656u * 4);
    unsigned int*   temp      = (unsigned int*)  (ws + 1900656u * 4);
    unsigned short* emb_b     = (unsigned short*)(ws + 3500656u * 4);
    float*          z         = (float*)         (ws + 6700656u * 4);
    float*          y1r       = (float*)         (ws + 13100656u * 4);
    unsigned short* h2b       = (unsigned short*)z;   // z dead after gemm1
    float*          z2        = y1r;                  // y1r dead after gemm2

    hipMemsetAsync(degi, 0, N_ENT * sizeof(int), stream);
    deg_count<<<NEDGE / 256, 256, 0, stream>>>(edges, degi);
    prep_k<<<N_ENT * 64 / 256, 256, 0, stream>>>(entity_emb, degi, dinv, emb_b);

    scan_partials<<<NBLK_SCAN, 256, 0, stream>>>(degi, partials);
    scan_offsets<<<1, 512, 0, stream>>>(partials, row_start);
    scan_apply<<<NBLK_SCAN, 256, 0, stream>>>(degi, partials, row_start);
    binit_k<<<1, 256, 0, stream>>>(row_start, gcursor);

    bin_k<<<NTILE, 256, 0, stream>>>(edges, gcursor, temp);
    unbin_k<<<NBUCK, 256, 0, stream>>>(temp, row_start, srcs);

    reduce1_k<<<N_ENT * 64 / 256, 256, 0, stream>>>(row_start, srcs, emb_b, dinv, z);
    gemm1_relu<<<N_ENT / 16, 256, 0, stream>>>(z, W1, b1, y1r);
    gemm2_k<<<N_ENT / 16, 256, 0, stream>>>(y1r, W2, dinv, h2b);
    reduce2_k<<<N_ENT * 64 / 256, 256, 0, stream>>>(row_start, srcs, h2b, dinv, b2, z2);

    final_dot<<<BATCH * 64 / 256, 256, 0, stream>>>(u, iidx, user_emb, z2, out);
}

// Round 8
// 418.285 us; speedup vs baseline: 1.4677x; 1.1240x over previous
//
#include <hip/hip_runtime.h>
#include <hip/hip_bf16.h>
#include <math.h>

// Problem constants (from reference)
constexpr int N_ENT = 100000;
constexpr int NEDGE = 1600000;
constexpr int BATCH = 8192;
constexpr int NBLK_SCAN = (N_ENT + 255) / 256;   // 391

// Bucketed CSR placement
constexpr int NBUCK = 256;
constexpr int KNODE = 391;                        // 256*391 >= N_ENT
constexpr int TILE  = 4096;
constexpr int NTILE = (NEDGE + TILE - 1) / TILE;  // 391

constexpr int NBLK_G = (N_ENT + 63) / 64;         // 1563 (64-row GEMM tiles)

// bf16 helpers (RNE pack, exact unpack)
__device__ inline unsigned short f2b(float x) {
    unsigned int u = __float_as_uint(x);
    unsigned int r = (u + 0x7fffu + ((u >> 16) & 1u)) >> 16;
    return (unsigned short)r;
}
__device__ inline float b2f(unsigned short h) {
    return __uint_as_float(((unsigned int)h) << 16);
}

// ---------------------------------------------------------------------------
// Workspace layout (4-byte units): same as R7.
//  degi[0,100000) dinv[100000,200000) row_start[200000,300001)
//  gcursor[300004,300260) partials[300264,300655) srcs[300656,1900656)
//  temp[1900656,3500656) emb_b(ushort)[3500656,6700656)
//  z/h2b[6700656,13100656) y1r/z2[13100656,25900656)

// K1: degree histogram
__global__ __launch_bounds__(256) void deg_count(const int* __restrict__ edges,
                                                 int* __restrict__ degi) {
    int e = blockIdx.x * 256 + threadIdx.x;
    if (e < NEDGE) atomicAdd(&degi[edges[NEDGE + e]], 1);
}

// K2: prep — dinv + premultiplied bf16 entity rows
__global__ __launch_bounds__(256) void prep_k(const float* __restrict__ emb,
                                              const int* __restrict__ degi,
                                              float* __restrict__ dinv,
                                              unsigned short* __restrict__ emb_b) {
    int gt   = blockIdx.x * 256 + threadIdx.x;
    int n    = gt >> 6;
    int lane = threadIdx.x & 63;
    float v = emb[(size_t)n * 64 + lane];
    float s = v * v;
#pragma unroll
    for (int o = 32; o > 0; o >>= 1) s += __shfl_xor(s, o, 64);
    float nrm = sqrtf(s);
    float sc  = nrm > 1.0f ? 1.0f / nrm : 1.0f;
    float dv  = 1.0f / sqrtf((float)(degi[n] + 1));
    if (lane == 0) dinv[n] = dv;
    emb_b[(size_t)n * 64 + lane] = f2b(sc * dv * v);
}

// K3a/b/c: hierarchical exclusive scan of degi -> row_start
__global__ __launch_bounds__(256) void scan_partials(const int* __restrict__ degi,
                                                     int* __restrict__ partials) {
    __shared__ int ws[4];
    int i = blockIdx.x * 256 + threadIdx.x;
    int v = (i < N_ENT) ? degi[i] : 0;
#pragma unroll
    for (int o = 32; o > 0; o >>= 1) v += __shfl_xor(v, o, 64);
    if ((threadIdx.x & 63) == 0) ws[threadIdx.x >> 6] = v;
    __syncthreads();
    if (threadIdx.x == 0) partials[blockIdx.x] = ws[0] + ws[1] + ws[2] + ws[3];
}

__global__ __launch_bounds__(512) void scan_offsets(int* __restrict__ partials,
                                                    int* __restrict__ row_start) {
    __shared__ int ts[512];
    int t = threadIdx.x;
    int v = (t < NBLK_SCAN) ? partials[t] : 0;
    ts[t] = v;
    __syncthreads();
    for (int off = 1; off < 512; off <<= 1) {
        int x = (t >= off) ? ts[t - off] : 0;
        __syncthreads();
        ts[t] += x;
        __syncthreads();
    }
    if (t < NBLK_SCAN) partials[t] = ts[t] - v;
    if (t == 0) row_start[N_ENT] = NEDGE;
}

__global__ __launch_bounds__(256) void scan_apply(const int* __restrict__ degi,
                                                  const int* __restrict__ partials,
                                                  int* __restrict__ row_start) {
    __shared__ int ts[256];
    int t = threadIdx.x;
    int i = blockIdx.x * 256 + t;
    int v = (i < N_ENT) ? degi[i] : 0;
    ts[t] = v;
    __syncthreads();
    for (int off = 1; off < 256; off <<= 1) {
        int x = (t >= off) ? ts[t - off] : 0;
        __syncthreads();
        ts[t] += x;
        __syncthreads();
    }
    if (i < N_ENT) row_start[i] = ts[t] - v + partials[blockIdx.x];
}

__global__ __launch_bounds__(256) void binit_k(const int* __restrict__ row_start,
                                               int* __restrict__ gcursor) {
    gcursor[threadIdx.x] = row_start[threadIdx.x * KNODE];
}

// K4a: bucket binning (contiguous per-(tile,bucket) runs -> covered lines)
__global__ __launch_bounds__(256) void bin_k(const int* __restrict__ edges,
                                             int* __restrict__ gcursor,
                                             unsigned int* __restrict__ temp) {
    __shared__ int cnt[NBUCK];
    __shared__ int gb[NBUCK];
    __shared__ int off[NBUCK];
    int tid  = threadIdx.x;
    int base = blockIdx.x * TILE;
    int sv[16], dv[16], bv[16];
    cnt[tid] = 0;
    __syncthreads();
#pragma unroll
    for (int i = 0; i < 16; ++i) {
        int e = base + i * 256 + tid;
        if (e < NEDGE) {
            sv[i] = edges[e];
            dv[i] = edges[NEDGE + e];
            bv[i] = dv[i] / KNODE;
            atomicAdd(&cnt[bv[i]], 1);
        } else {
            bv[i] = -1;
        }
    }
    __syncthreads();
    if (cnt[tid] > 0) gb[tid] = atomicAdd(&gcursor[tid], cnt[tid]);
    off[tid] = 0;
    __syncthreads();
#pragma unroll
    for (int i = 0; i < 16; ++i) {
        int b = bv[i];
        if (b >= 0) {
            int p  = atomicAdd(&off[b], 1);
            int dl = dv[i] - b * KNODE;
            temp[gb[b] + p] = ((unsigned int)sv[i] << 9) | (unsigned int)dl;
        }
    }
}

// K4b: within-bucket placement
__global__ __launch_bounds__(256) void unbin_k(const unsigned int* __restrict__ temp,
                                               const int* __restrict__ row_start,
                                               int* __restrict__ srcs) {
    __shared__ int cur[KNODE];
    int b     = blockIdx.x;
    int node0 = b * KNODE;
    int nn    = N_ENT - node0; if (nn > KNODE) nn = KNODE;
    for (int i = threadIdx.x; i < nn; i += 256) cur[i] = row_start[node0 + i];
    __syncthreads();
    int rbeg = row_start[node0];
    int rend = row_start[node0 + nn];
    for (int idx = rbeg + threadIdx.x; idx < rend; idx += 256) {
        unsigned int v = temp[idx];
        int dl = (int)(v & 511u);
        int s  = (int)(v >> 9);
        int pos = atomicAdd(&cur[dl], 1);
        srcs[pos] = s;
    }
}

// K5: layer-1 aggregate: z[d] = dinv[d] * (sum_j emb_b[s_j] + emb_b[d])
__global__ __launch_bounds__(256) void reduce1_k(const int* __restrict__ row_start,
                                                 const int* __restrict__ srcs,
                                                 const unsigned short* __restrict__ emb_b,
                                                 const float* __restrict__ dinv,
                                                 float* __restrict__ z) {
    int gt   = blockIdx.x * 256 + threadIdx.x;
    int dst  = gt >> 6;
    int lane = threadIdx.x & 63;
    int beg = row_start[dst];
    int end = row_start[dst + 1];
    float a0 = 0.f, a1 = 0.f, a2 = 0.f, a3 = 0.f;
    for (int base = beg; base < end; base += 64) {
        int cnt = end - base; if (cnt > 64) cnt = 64;
        int s_v = (base + lane < end) ? srcs[base + lane] : 0;
        int jj = 0;
        for (; jj + 3 < cnt; jj += 4) {
            int s0 = __shfl(s_v, jj, 64),     s1 = __shfl(s_v, jj + 1, 64);
            int s2 = __shfl(s_v, jj + 2, 64), s3 = __shfl(s_v, jj + 3, 64);
            a0 += b2f(emb_b[(size_t)s0 * 64 + lane]);
            a1 += b2f(emb_b[(size_t)s1 * 64 + lane]);
            a2 += b2f(emb_b[(size_t)s2 * 64 + lane]);
            a3 += b2f(emb_b[(size_t)s3 * 64 + lane]);
        }
        for (; jj < cnt; ++jj) {
            int s0 = __shfl(s_v, jj, 64);
            a0 += b2f(emb_b[(size_t)s0 * 64 + lane]);
        }
    }
    float own = b2f(emb_b[(size_t)dst * 64 + lane]);
    z[(size_t)dst * 64 + lane] = dinv[dst] * (a0 + a1 + a2 + a3 + own);
}

// K6: y1r = relu(z @ W1 + b1)  [N,64]@[64,128] — register-blocked 8x4/thread.
// LDS reads per 4 k-steps: 8 broadcast b128 (A) + 4 spread b128 (W) per 128
// FMAs (~0.09 reads/FMA vs 1.25 in the R7 version, which was LDS-bound).
__global__ __launch_bounds__(256) void gemm1_relu(const float* __restrict__ z,
                                                  const float* __restrict__ W1g,
                                                  const float* __restrict__ b1,
                                                  float* __restrict__ y1r) {
    __shared__ float As[64 * 68];     // stride 68 floats (17 float4)
    __shared__ float Ws[64 * 132];    // stride 132 floats (33 float4)
    int tid  = threadIdx.x;
    int row0 = blockIdx.x * 64;
    // stage A (64x64) — 1024 float4
    for (int idx = tid; idx < 1024; idx += 256) {
        int r = idx >> 4, c4 = (idx & 15) * 4;
        int grow = row0 + r;
        float4 v = make_float4(0.f, 0.f, 0.f, 0.f);
        if (grow < N_ENT) v = *(const float4*)(z + (size_t)grow * 64 + c4);
        *(float4*)(As + r * 68 + c4) = v;
    }
    // stage W1 (64x128) — 2048 float4
    for (int idx = tid; idx < 2048; idx += 256) {
        int k = idx >> 5, c4 = (idx & 31) * 4;
        *(float4*)(Ws + k * 132 + c4) = *(const float4*)(W1g + k * 128 + c4);
    }
    __syncthreads();

    int cg = tid & 31;        // col group: c0 = 4*cg
    int rg = tid >> 5;        // row group: r0 = 8*rg
    int c0 = cg * 4;
    int r0 = rg * 8;
    const float4* A4 = (const float4*)As;   // row stride 17
    const float4* W4 = (const float4*)Ws;   // row stride 33
    float acc[8][4];
#pragma unroll
    for (int i = 0; i < 8; ++i)
#pragma unroll
        for (int j = 0; j < 4; ++j) acc[i][j] = 0.f;

    for (int k4 = 0; k4 < 16; ++k4) {
        float4 w0 = W4[(4 * k4 + 0) * 33 + cg];
        float4 w1 = W4[(4 * k4 + 1) * 33 + cg];
        float4 w2 = W4[(4 * k4 + 2) * 33 + cg];
        float4 w3 = W4[(4 * k4 + 3) * 33 + cg];
#pragma unroll
        for (int i = 0; i < 8; ++i) {
            float4 a = A4[(r0 + i) * 17 + k4];
            acc[i][0] += a.x * w0.x + a.y * w1.x + a.z * w2.x + a.w * w3.x;
            acc[i][1] += a.x * w0.y + a.y * w1.y + a.z * w2.y + a.w * w3.y;
            acc[i][2] += a.x * w0.z + a.y * w1.z + a.z * w2.z + a.w * w3.z;
            acc[i][3] += a.x * w0.w + a.y * w1.w + a.z * w2.w + a.w * w3.w;
        }
    }
    float4 bb = *(const float4*)(b1 + c0);
#pragma unroll
    for (int i = 0; i < 8; ++i) {
        int grow = row0 + r0 + i;
        if (grow < N_ENT) {
            float4 o;
            o.x = fmaxf(acc[i][0] + bb.x, 0.f);
            o.y = fmaxf(acc[i][1] + bb.y, 0.f);
            o.z = fmaxf(acc[i][2] + bb.z, 0.f);
            o.w = fmaxf(acc[i][3] + bb.w, 0.f);
            *(float4*)(y1r + (size_t)grow * 128 + c0) = o;
        }
    }
}

// K7: h2b = bf16(dinv[row]*(y1r @ W2))  [N,128]@[128,64] — 4x4/thread.
__global__ __launch_bounds__(256) void gemm2_k(const float* __restrict__ y1r,
                                               const float* __restrict__ W2g,
                                               const float* __restrict__ dinv,
                                               unsigned short* __restrict__ h2b) {
    __shared__ float Ys[64 * 132];    // stride 132 (33 float4)
    __shared__ float Ws[128 * 68];    // stride 68 (17 float4)
    int tid  = threadIdx.x;
    int row0 = blockIdx.x * 64;
    // stage Y (64x128) — 2048 float4
    for (int idx = tid; idx < 2048; idx += 256) {
        int r = idx >> 5, c4 = (idx & 31) * 4;
        int grow = row0 + r;
        float4 v = make_float4(0.f, 0.f, 0.f, 0.f);
        if (grow < N_ENT) v = *(const float4*)(y1r + (size_t)grow * 128 + c4);
        *(float4*)(Ys + r * 132 + c4) = v;
    }
    // stage W2 (128x64) — 2048 float4
    for (int idx = tid; idx < 2048; idx += 256) {
        int k = idx >> 4, c4 = (idx & 15) * 4;
        *(float4*)(Ws + k * 68 + c4) = *(const float4*)(W2g + k * 64 + c4);
    }
    __syncthreads();

    int cg = tid & 15;        // c0 = 4*cg (out cols 0..63)
    int rg = tid >> 4;        // r0 = 4*rg (rows 0..63)
    int c0 = cg * 4;
    int r0 = rg * 4;
    const float4* Y4 = (const float4*)Ys;   // row stride 33
    const float4* W4 = (const float4*)Ws;   // row stride 17
    float acc[4][4];
#pragma unroll
    for (int i = 0; i < 4; ++i)
#pragma unroll
        for (int j = 0; j < 4; ++j) acc[i][j] = 0.f;

    for (int k4 = 0; k4 < 32; ++k4) {
        float4 w0 = W4[(4 * k4 + 0) * 17 + cg];
        float4 w1 = W4[(4 * k4 + 1) * 17 + cg];
        float4 w2 = W4[(4 * k4 + 2) * 17 + cg];
        float4 w3 = W4[(4 * k4 + 3) * 17 + cg];
#pragma unroll
        for (int i = 0; i < 4; ++i) {
            float4 a = Y4[(r0 + i) * 33 + k4];
            acc[i][0] += a.x * w0.x + a.y * w1.x + a.z * w2.x + a.w * w3.x;
            acc[i][1] += a.x * w0.y + a.y * w1.y + a.z * w2.y + a.w * w3.y;
            acc[i][2] += a.x * w0.z + a.y * w1.z + a.z * w2.z + a.w * w3.z;
            acc[i][3] += a.x * w0.w + a.y * w1.w + a.z * w2.w + a.w * w3.w;
        }
    }
#pragma unroll
    for (int i = 0; i < 4; ++i) {
        int grow = row0 + r0 + i;
        if (grow < N_ENT) {
            float dv = dinv[grow];
            unsigned int h0 = f2b(acc[i][0] * dv);
            unsigned int h1 = f2b(acc[i][1] * dv);
            unsigned int h2 = f2b(acc[i][2] * dv);
            unsigned int h3 = f2b(acc[i][3] * dv);
            uint2 p;
            p.x = h0 | (h1 << 16);
            p.y = h2 | (h3 << 16);
            *(uint2*)(h2b + (size_t)grow * 64 + c0) = p;
        }
    }
}

// K8: layer-2 aggregate: z2[d] = dinv[d]*(sum_j h2b[s_j] + h2b[d]) + b2
__global__ __launch_bounds__(256) void reduce2_k(const int* __restrict__ row_start,
                                                 const int* __restrict__ srcs,
                                                 const unsigned short* __restrict__ h2b,
                                                 const float* __restrict__ dinv,
                                                 const float* __restrict__ b2,
                                                 float* __restrict__ z2) {
    int gt   = blockIdx.x * 256 + threadIdx.x;
    int dst  = gt >> 6;
    int lane = threadIdx.x & 63;
    int beg = row_start[dst];
    int end = row_start[dst + 1];
    float a0 = 0.f, a1 = 0.f, a2 = 0.f, a3 = 0.f;
    for (int base = beg; base < end; base += 64) {
        int cnt = end - base; if (cnt > 64) cnt = 64;
        int s_v = (base + lane < end) ? srcs[base + lane] : 0;
        int jj = 0;
        for (; jj + 3 < cnt; jj += 4) {
            int s0 = __shfl(s_v, jj, 64),     s1 = __shfl(s_v, jj + 1, 64);
            int s2 = __shfl(s_v, jj + 2, 64), s3 = __shfl(s_v, jj + 3, 64);
            a0 += b2f(h2b[(size_t)s0 * 64 + lane]);
            a1 += b2f(h2b[(size_t)s1 * 64 + lane]);
            a2 += b2f(h2b[(size_t)s2 * 64 + lane]);
            a3 += b2f(h2b[(size_t)s3 * 64 + lane]);
        }
        for (; jj < cnt; ++jj) {
            int s0 = __shfl(s_v, jj, 64);
            a0 += b2f(h2b[(size_t)s0 * 64 + lane]);
        }
    }
    float own = b2f(h2b[(size_t)dst * 64 + lane]);
    z2[(size_t)dst * 64 + lane] =
        dinv[dst] * (a0 + a1 + a2 + a3 + own) + b2[lane];
}

// K9: final — renorm(user)·item, sigmoid; one wave per batch element
__global__ __launch_bounds__(256) void final_dot(const int* __restrict__ u,
                                                 const int* __restrict__ iidx,
                                                 const float* __restrict__ uemb,
                                                 const float* __restrict__ z2,
                                                 float* __restrict__ out) {
    int gt   = blockIdx.x * 256 + threadIdx.x;
    int b    = gt >> 6;
    int lane = threadIdx.x & 63;
    int ui = u[b];
    int it = iidx[b];
    float ue = uemb[(size_t)ui * 64 + lane];
    float iv = z2[(size_t)it * 64 + lane];
    float s1 = ue * ue;
    float s2 = ue * iv;
#pragma unroll
    for (int o = 32; o > 0; o >>= 1) {
        s1 += __shfl_xor(s1, o, 64);
        s2 += __shfl_xor(s2, o, 64);
    }
    if (lane == 0) {
        float nrm = sqrtf(s1);
        float sc  = nrm > 1.0f ? 1.0f / nrm : 1.0f;
        float uv  = s2 * sc;
        out[b] = 1.0f / (1.0f + expf(-uv));
    }
}

// ---------------------------------------------------------------------------
extern "C" void kernel_launch(void* const* d_in, const int* in_sizes, int n_in,
                              void* d_out, int out_size, void* d_ws, size_t ws_size,
                              hipStream_t stream) {
    const int*   u          = (const int*)d_in[0];
    const int*   iidx       = (const int*)d_in[1];
    const int*   edges      = (const int*)d_in[2];
    const float* user_emb   = (const float*)d_in[3];
    const float* entity_emb = (const float*)d_in[4];
    const float* W1         = (const float*)d_in[5];
    const float* b1         = (const float*)d_in[6];
    const float* W2         = (const float*)d_in[7];
    const float* b2         = (const float*)d_in[8];
    float*       out        = (float*)d_out;

    char* ws = (char*)d_ws;
    int*            degi      = (int*)           (ws);
    float*          dinv      = (float*)         (ws + 100000u * 4);
    int*            row_start = (int*)           (ws + 200000u * 4);
    int*            gcursor   = (int*)           (ws + 300004u * 4);
    int*            partials  = (int*)           (ws + 300264u * 4);
    int*            srcs      = (int*)           (ws + 300656u * 4);
    unsigned int*   temp      = (unsigned int*)  (ws + 1900656u * 4);
    unsigned short* emb_b     = (unsigned short*)(ws + 3500656u * 4);
    float*          z         = (float*)         (ws + 6700656u * 4);
    float*          y1r       = (float*)         (ws + 13100656u * 4);
    unsigned short* h2b       = (unsigned short*)z;   // z dead after gemm1
    float*          z2        = y1r;                  // y1r dead after gemm2

    hipMemsetAsync(degi, 0, N_ENT * sizeof(int), stream);
    deg_count<<<NEDGE / 256, 256, 0, stream>>>(edges, degi);
    prep_k<<<N_ENT * 64 / 256, 256, 0, stream>>>(entity_emb, degi, dinv, emb_b);

    scan_partials<<<NBLK_SCAN, 256, 0, stream>>>(degi, partials);
    scan_offsets<<<1, 512, 0, stream>>>(partials, row_start);
    scan_apply<<<NBLK_SCAN, 256, 0, stream>>>(degi, partials, row_start);
    binit_k<<<1, 256, 0, stream>>>(row_start, gcursor);

    bin_k<<<NTILE, 256, 0, stream>>>(edges, gcursor, temp);
    unbin_k<<<NBUCK, 256, 0, stream>>>(temp, row_start, srcs);

    reduce1_k<<<N_ENT * 64 / 256, 256, 0, stream>>>(row_start, srcs, emb_b, dinv, z);
    gemm1_relu<<<NBLK_G, 256, 0, stream>>>(z, W1, b1, y1r);
    gemm2_k<<<NBLK_G, 256, 0, stream>>>(y1r, W2, dinv, h2b);
    reduce2_k<<<N_ENT * 64 / 256, 256, 0, stream>>>(row_start, srcs, h2b, dinv, b2, z2);

    final_dot<<<BATCH * 64 / 256, 256, 0, stream>>>(u, iidx, user_emb, z2, out);
}

// Round 9
// 363.226 us; speedup vs baseline: 1.6902x; 1.1516x over previous
//
#include <hip/hip_runtime.h>
#include <hip/hip_bf16.h>
#include <math.h>

// Problem constants (from reference)
constexpr int N_ENT = 100000;
constexpr int NEDGE = 1600000;
constexpr int BATCH = 8192;
constexpr int NBLK_SCAN = (N_ENT + 255) / 256;   // 391

// Bucketed CSR placement
constexpr int NBUCK   = 256;
constexpr int KNODE   = 391;                      // 256*391 >= N_ENT
constexpr int TILE    = 4096;
constexpr int NTILE   = (NEDGE + TILE - 1) / TILE; // 391
constexpr int BUCKCAP = 8192;                     // fixed bucket region (mean 6250, +24 sigma)

constexpr int NBLK_G = (N_ENT + 63) / 64;         // 1563 (64-row GEMM tiles)

// bf16 helpers (RNE pack, exact unpack)
__device__ inline unsigned short f2b(float x) {
    unsigned int u = __float_as_uint(x);
    unsigned int r = (u + 0x7fffu + ((u >> 16) & 1u)) >> 16;
    return (unsigned short)r;
}
__device__ inline float b2f(unsigned short h) {
    return __uint_as_float(((unsigned int)h) << 16);
}

// ---------------------------------------------------------------------------
// Workspace layout (4-byte units):
//  degi      : [0, 100000)
//  dinv      : [100000, 200000)
//  row_start : [200000, 300001)
//  gcursor   : [300004, 300260)
//  partials  : [300264, 300655)
//  srcs      : [300656, 1900656)
//  emb_b     : [1900656, 5100656)   ushort[N*64]
//  z / h2b   : [5100656, 11500656)  float [N,64]; h2b reuses
//  y1r/z2/temp:[11500656, 24300656) float [N,128]; temp (2.1M uint) overlaps
//                                   the y1r region (dead until gemm1)
// Total ~97.2 MB.

// K1: prep — dinv + premultiplied bf16 entity rows (needs degi from count_k)
__global__ __launch_bounds__(256) void prep_k(const float* __restrict__ emb,
                                              const int* __restrict__ degi,
                                              float* __restrict__ dinv,
                                              unsigned short* __restrict__ emb_b) {
    int gt   = blockIdx.x * 256 + threadIdx.x;
    int n    = gt >> 6;
    int lane = threadIdx.x & 63;
    float v = emb[(size_t)n * 64 + lane];
    float s = v * v;
#pragma unroll
    for (int o = 32; o > 0; o >>= 1) s += __shfl_xor(s, o, 64);
    float nrm = sqrtf(s);
    float sc  = nrm > 1.0f ? 1.0f / nrm : 1.0f;
    float dv  = 1.0f / sqrtf((float)(degi[n] + 1));
    if (lane == 0) dinv[n] = dv;
    emb_b[(size_t)n * 64 + lane] = f2b(sc * dv * v);
}

// K0a: gcursor init to fixed bucket bases
__global__ __launch_bounds__(256) void ginit_k(int* __restrict__ gcursor) {
    gcursor[threadIdx.x] = threadIdx.x * BUCKCAP;
}

// K0b: bucket binning into fixed-capacity regions (no row_start dependency).
// Contiguous per-(tile,bucket) runs -> dirtied lines fully covered ->
// payload-granular HBM writeback.
__global__ __launch_bounds__(256) void bin_k(const int* __restrict__ edges,
                                             int* __restrict__ gcursor,
                                             unsigned int* __restrict__ temp) {
    __shared__ int cnt[NBUCK];
    __shared__ int gb[NBUCK];
    __shared__ int off[NBUCK];
    int tid  = threadIdx.x;
    int base = blockIdx.x * TILE;
    int sv[16], dv[16], bv[16];
    cnt[tid] = 0;
    __syncthreads();
#pragma unroll
    for (int i = 0; i < 16; ++i) {
        int e = base + i * 256 + tid;
        if (e < NEDGE) {
            sv[i] = edges[e];
            dv[i] = edges[NEDGE + e];
            bv[i] = dv[i] / KNODE;
            atomicAdd(&cnt[bv[i]], 1);
        } else {
            bv[i] = -1;
        }
    }
    __syncthreads();
    if (cnt[tid] > 0) gb[tid] = atomicAdd(&gcursor[tid], cnt[tid]);
    off[tid] = 0;
    __syncthreads();
#pragma unroll
    for (int i = 0; i < 16; ++i) {
        int b = bv[i];
        if (b >= 0) {
            int p  = atomicAdd(&off[b], 1);
            int dl = dv[i] - b * KNODE;
            temp[gb[b] + p] = ((unsigned int)sv[i] << 9) | (unsigned int)dl;
        }
    }
}

// K0c: per-bucket degree histogram from binned temp — replaces the global
// scattered-atomic deg_count (which cost 66 us / 50 MB atomic writeback).
// Coalesced temp read + LDS atomics + coalesced degi write.
__global__ __launch_bounds__(256) void count_k(const unsigned int* __restrict__ temp,
                                               const int* __restrict__ gcursor,
                                               int* __restrict__ degi) {
    __shared__ int cnt[KNODE];
    int b     = blockIdx.x;
    int node0 = b * KNODE;
    int nn    = N_ENT - node0; if (nn > KNODE) nn = KNODE;
    for (int i = threadIdx.x; i < KNODE; i += 256) cnt[i] = 0;
    __syncthreads();
    int tbeg = b * BUCKCAP;
    int tend = gcursor[b];
    for (int idx = tbeg + threadIdx.x; idx < tend; idx += 256)
        atomicAdd(&cnt[temp[idx] & 511u], 1);
    __syncthreads();
    for (int i = threadIdx.x; i < nn; i += 256) degi[node0 + i] = cnt[i];
}

// K3a/b/c: hierarchical exclusive scan of degi -> row_start
__global__ __launch_bounds__(256) void scan_partials(const int* __restrict__ degi,
                                                     int* __restrict__ partials) {
    __shared__ int ws[4];
    int i = blockIdx.x * 256 + threadIdx.x;
    int v = (i < N_ENT) ? degi[i] : 0;
#pragma unroll
    for (int o = 32; o > 0; o >>= 1) v += __shfl_xor(v, o, 64);
    if ((threadIdx.x & 63) == 0) ws[threadIdx.x >> 6] = v;
    __syncthreads();
    if (threadIdx.x == 0) partials[blockIdx.x] = ws[0] + ws[1] + ws[2] + ws[3];
}

__global__ __launch_bounds__(512) void scan_offsets(int* __restrict__ partials,
                                                    int* __restrict__ row_start) {
    __shared__ int ts[512];
    int t = threadIdx.x;
    int v = (t < NBLK_SCAN) ? partials[t] : 0;
    ts[t] = v;
    __syncthreads();
    for (int off = 1; off < 512; off <<= 1) {
        int x = (t >= off) ? ts[t - off] : 0;
        __syncthreads();
        ts[t] += x;
        __syncthreads();
    }
    if (t < NBLK_SCAN) partials[t] = ts[t] - v;
    if (t == 0) row_start[N_ENT] = NEDGE;
}

__global__ __launch_bounds__(256) void scan_apply(const int* __restrict__ degi,
                                                  const int* __restrict__ partials,
                                                  int* __restrict__ row_start) {
    __shared__ int ts[256];
    int t = threadIdx.x;
    int i = blockIdx.x * 256 + t;
    int v = (i < N_ENT) ? degi[i] : 0;
    ts[t] = v;
    __syncthreads();
    for (int off = 1; off < 256; off <<= 1) {
        int x = (t >= off) ? ts[t - off] : 0;
        __syncthreads();
        ts[t] += x;
        __syncthreads();
    }
    if (i < N_ENT) row_start[i] = ts[t] - v + partials[blockIdx.x];
}

// K4b: within-bucket placement (writes confined to contiguous region)
__global__ __launch_bounds__(256) void unbin_k(const unsigned int* __restrict__ temp,
                                               const int* __restrict__ gcursor,
                                               const int* __restrict__ row_start,
                                               int* __restrict__ srcs) {
    __shared__ int cur[KNODE];
    int b     = blockIdx.x;
    int node0 = b * KNODE;
    int nn    = N_ENT - node0; if (nn > KNODE) nn = KNODE;
    for (int i = threadIdx.x; i < nn; i += 256) cur[i] = row_start[node0 + i];
    __syncthreads();
    int tbeg = b * BUCKCAP;
    int tend = gcursor[b];
    for (int idx = tbeg + threadIdx.x; idx < tend; idx += 256) {
        unsigned int v = temp[idx];
        int dl = (int)(v & 511u);
        int s  = (int)(v >> 9);
        int pos = atomicAdd(&cur[dl], 1);
        srcs[pos] = s;
    }
}

// K5: layer-1 aggregate: z[d] = dinv[d] * (sum_j emb_b[s_j] + emb_b[d])
__global__ __launch_bounds__(256) void reduce1_k(const int* __restrict__ row_start,
                                                 const int* __restrict__ srcs,
                                                 const unsigned short* __restrict__ emb_b,
                                                 const float* __restrict__ dinv,
                                                 float* __restrict__ z) {
    int gt   = blockIdx.x * 256 + threadIdx.x;
    int dst  = gt >> 6;
    int lane = threadIdx.x & 63;
    int beg = row_start[dst];
    int end = row_start[dst + 1];
    float a0 = 0.f, a1 = 0.f, a2 = 0.f, a3 = 0.f;
    for (int base = beg; base < end; base += 64) {
        int cnt = end - base; if (cnt > 64) cnt = 64;
        int s_v = (base + lane < end) ? srcs[base + lane] : 0;
        int jj = 0;
        for (; jj + 3 < cnt; jj += 4) {
            int s0 = __shfl(s_v, jj, 64),     s1 = __shfl(s_v, jj + 1, 64);
            int s2 = __shfl(s_v, jj + 2, 64), s3 = __shfl(s_v, jj + 3, 64);
            a0 += b2f(emb_b[(size_t)s0 * 64 + lane]);
            a1 += b2f(emb_b[(size_t)s1 * 64 + lane]);
            a2 += b2f(emb_b[(size_t)s2 * 64 + lane]);
            a3 += b2f(emb_b[(size_t)s3 * 64 + lane]);
        }
        for (; jj < cnt; ++jj) {
            int s0 = __shfl(s_v, jj, 64);
            a0 += b2f(emb_b[(size_t)s0 * 64 + lane]);
        }
    }
    float own = b2f(emb_b[(size_t)dst * 64 + lane]);
    z[(size_t)dst * 64 + lane] = dinv[dst] * (a0 + a1 + a2 + a3 + own);
}

// K6: y1r = relu(z @ W1 + b1)  [N,64]@[64,128] — register-blocked 8x4/thread.
__global__ __launch_bounds__(256) void gemm1_relu(const float* __restrict__ z,
                                                  const float* __restrict__ W1g,
                                                  const float* __restrict__ b1,
                                                  float* __restrict__ y1r) {
    __shared__ float As[64 * 68];     // stride 68 floats (17 float4)
    __shared__ float Ws[64 * 132];    // stride 132 floats (33 float4)
    int tid  = threadIdx.x;
    int row0 = blockIdx.x * 64;
    for (int idx = tid; idx < 1024; idx += 256) {
        int r = idx >> 4, c4 = (idx & 15) * 4;
        int grow = row0 + r;
        float4 v = make_float4(0.f, 0.f, 0.f, 0.f);
        if (grow < N_ENT) v = *(const float4*)(z + (size_t)grow * 64 + c4);
        *(float4*)(As + r * 68 + c4) = v;
    }
    for (int idx = tid; idx < 2048; idx += 256) {
        int k = idx >> 5, c4 = (idx & 31) * 4;
        *(float4*)(Ws + k * 132 + c4) = *(const float4*)(W1g + k * 128 + c4);
    }
    __syncthreads();

    int cg = tid & 31;
    int rg = tid >> 5;
    int c0 = cg * 4;
    int r0 = rg * 8;
    const float4* A4 = (const float4*)As;   // row stride 17
    const float4* W4 = (const float4*)Ws;   // row stride 33
    float acc[8][4];
#pragma unroll
    for (int i = 0; i < 8; ++i)
#pragma unroll
        for (int j = 0; j < 4; ++j) acc[i][j] = 0.f;

    for (int k4 = 0; k4 < 16; ++k4) {
        float4 w0 = W4[(4 * k4 + 0) * 33 + cg];
        float4 w1 = W4[(4 * k4 + 1) * 33 + cg];
        float4 w2 = W4[(4 * k4 + 2) * 33 + cg];
        float4 w3 = W4[(4 * k4 + 3) * 33 + cg];
#pragma unroll
        for (int i = 0; i < 8; ++i) {
            float4 a = A4[(r0 + i) * 17 + k4];
            acc[i][0] += a.x * w0.x + a.y * w1.x + a.z * w2.x + a.w * w3.x;
            acc[i][1] += a.x * w0.y + a.y * w1.y + a.z * w2.y + a.w * w3.y;
            acc[i][2] += a.x * w0.z + a.y * w1.z + a.z * w2.z + a.w * w3.z;
            acc[i][3] += a.x * w0.w + a.y * w1.w + a.z * w2.w + a.w * w3.w;
        }
    }
    float4 bb = *(const float4*)(b1 + c0);
#pragma unroll
    for (int i = 0; i < 8; ++i) {
        int grow = row0 + r0 + i;
        if (grow < N_ENT) {
            float4 o;
            o.x = fmaxf(acc[i][0] + bb.x, 0.f);
            o.y = fmaxf(acc[i][1] + bb.y, 0.f);
            o.z = fmaxf(acc[i][2] + bb.z, 0.f);
            o.w = fmaxf(acc[i][3] + bb.w, 0.f);
            *(float4*)(y1r + (size_t)grow * 128 + c0) = o;
        }
    }
}

// K7: h2b = bf16(dinv[row]*(y1r @ W2))  [N,128]@[128,64] — 4x4/thread.
__global__ __launch_bounds__(256) void gemm2_k(const float* __restrict__ y1r,
                                               const float* __restrict__ W2g,
                                               const float* __restrict__ dinv,
                                               unsigned short* __restrict__ h2b) {
    __shared__ float Ys[64 * 132];
    __shared__ float Ws[128 * 68];
    int tid  = threadIdx.x;
    int row0 = blockIdx.x * 64;
    for (int idx = tid; idx < 2048; idx += 256) {
        int r = idx >> 5, c4 = (idx & 31) * 4;
        int grow = row0 + r;
        float4 v = make_float4(0.f, 0.f, 0.f, 0.f);
        if (grow < N_ENT) v = *(const float4*)(y1r + (size_t)grow * 128 + c4);
        *(float4*)(Ys + r * 132 + c4) = v;
    }
    for (int idx = tid; idx < 2048; idx += 256) {
        int k = idx >> 4, c4 = (idx & 15) * 4;
        *(float4*)(Ws + k * 68 + c4) = *(const float4*)(W2g + k * 64 + c4);
    }
    __syncthreads();

    int cg = tid & 15;
    int rg = tid >> 4;
    int c0 = cg * 4;
    int r0 = rg * 4;
    const float4* Y4 = (const float4*)Ys;   // row stride 33
    const float4* W4 = (const float4*)Ws;   // row stride 17
    float acc[4][4];
#pragma unroll
    for (int i = 0; i < 4; ++i)
#pragma unroll
        for (int j = 0; j < 4; ++j) acc[i][j] = 0.f;

    for (int k4 = 0; k4 < 32; ++k4) {
        float4 w0 = W4[(4 * k4 + 0) * 17 + cg];
        float4 w1 = W4[(4 * k4 + 1) * 17 + cg];
        float4 w2 = W4[(4 * k4 + 2) * 17 + cg];
        float4 w3 = W4[(4 * k4 + 3) * 17 + cg];
#pragma unroll
        for (int i = 0; i < 4; ++i) {
            float4 a = Y4[(r0 + i) * 33 + k4];
            acc[i][0] += a.x * w0.x + a.y * w1.x + a.z * w2.x + a.w * w3.x;
            acc[i][1] += a.x * w0.y + a.y * w1.y + a.z * w2.y + a.w * w3.y;
            acc[i][2] += a.x * w0.z + a.y * w1.z + a.z * w2.z + a.w * w3.z;
            acc[i][3] += a.x * w0.w + a.y * w1.w + a.z * w2.w + a.w * w3.w;
        }
    }
#pragma unroll
    for (int i = 0; i < 4; ++i) {
        int grow = row0 + r0 + i;
        if (grow < N_ENT) {
            float dv = dinv[grow];
            unsigned int h0 = f2b(acc[i][0] * dv);
            unsigned int h1 = f2b(acc[i][1] * dv);
            unsigned int h2 = f2b(acc[i][2] * dv);
            unsigned int h3 = f2b(acc[i][3] * dv);
            uint2 p;
            p.x = h0 | (h1 << 16);
            p.y = h2 | (h3 << 16);
            *(uint2*)(h2b + (size_t)grow * 64 + c0) = p;
        }
    }
}

// K8: layer-2 aggregate: z2[d] = dinv[d]*(sum_j h2b[s_j] + h2b[d]) + b2
__global__ __launch_bounds__(256) void reduce2_k(const int* __restrict__ row_start,
                                                 const int* __restrict__ srcs,
                                                 const unsigned short* __restrict__ h2b,
                                                 const float* __restrict__ dinv,
                                                 const float* __restrict__ b2,
                                                 float* __restrict__ z2) {
    int gt   = blockIdx.x * 256 + threadIdx.x;
    int dst  = gt >> 6;
    int lane = threadIdx.x & 63;
    int beg = row_start[dst];
    int end = row_start[dst + 1];
    float a0 = 0.f, a1 = 0.f, a2 = 0.f, a3 = 0.f;
    for (int base = beg; base < end; base += 64) {
        int cnt = end - base; if (cnt > 64) cnt = 64;
        int s_v = (base + lane < end) ? srcs[base + lane] : 0;
        int jj = 0;
        for (; jj + 3 < cnt; jj += 4) {
            int s0 = __shfl(s_v, jj, 64),     s1 = __shfl(s_v, jj + 1, 64);
            int s2 = __shfl(s_v, jj + 2, 64), s3 = __shfl(s_v, jj + 3, 64);
            a0 += b2f(h2b[(size_t)s0 * 64 + lane]);
            a1 += b2f(h2b[(size_t)s1 * 64 + lane]);
            a2 += b2f(h2b[(size_t)s2 * 64 + lane]);
            a3 += b2f(h2b[(size_t)s3 * 64 + lane]);
        }
        for (; jj < cnt; ++jj) {
            int s0 = __shfl(s_v, jj, 64);
            a0 += b2f(h2b[(size_t)s0 * 64 + lane]);
        }
    }
    float own = b2f(h2b[(size_t)dst * 64 + lane]);
    z2[(size_t)dst * 64 + lane] =
        dinv[dst] * (a0 + a1 + a2 + a3 + own) + b2[lane];
}

// K9: final — renorm(user)·item, sigmoid; one wave per batch element
__global__ __launch_bounds__(256) void final_dot(const int* __restrict__ u,
                                                 const int* __restrict__ iidx,
                                                 const float* __restrict__ uemb,
                                                 const float* __restrict__ z2,
                                                 float* __restrict__ out) {
    int gt   = blockIdx.x * 256 + threadIdx.x;
    int b    = gt >> 6;
    int lane = threadIdx.x & 63;
    int ui = u[b];
    int it = iidx[b];
    float ue = uemb[(size_t)ui * 64 + lane];
    float iv = z2[(size_t)it * 64 + lane];
    float s1 = ue * ue;
    float s2 = ue * iv;
#pragma unroll
    for (int o = 32; o > 0; o >>= 1) {
        s1 += __shfl_xor(s1, o, 64);
        s2 += __shfl_xor(s2, o, 64);
    }
    if (lane == 0) {
        float nrm = sqrtf(s1);
        float sc  = nrm > 1.0f ? 1.0f / nrm : 1.0f;
        float uv  = s2 * sc;
        out[b] = 1.0f / (1.0f + expf(-uv));
    }
}

// ---------------------------------------------------------------------------
extern "C" void kernel_launch(void* const* d_in, const int* in_sizes, int n_in,
                              void* d_out, int out_size, void* d_ws, size_t ws_size,
                              hipStream_t stream) {
    const int*   u          = (const int*)d_in[0];
    const int*   iidx       = (const int*)d_in[1];
    const int*   edges      = (const int*)d_in[2];
    const float* user_emb   = (const float*)d_in[3];
    const float* entity_emb = (const float*)d_in[4];
    const float* W1         = (const float*)d_in[5];
    const float* b1         = (const float*)d_in[6];
    const float* W2         = (const float*)d_in[7];
    const float* b2         = (const float*)d_in[8];
    float*       out        = (float*)d_out;

    char* ws = (char*)d_ws;
    int*            degi      = (int*)           (ws);
    float*          dinv      = (float*)         (ws + 100000u * 4);
    int*            row_start = (int*)           (ws + 200000u * 4);
    int*            gcursor   = (int*)           (ws + 300004u * 4);
    int*            partials  = (int*)           (ws + 300264u * 4);
    int*            srcs      = (int*)           (ws + 300656u * 4);
    unsigned short* emb_b     = (unsigned short*)(ws + 1900656u * 4);
    float*          z         = (float*)         (ws + 5100656u * 4);
    float*          y1r       = (float*)         (ws + 11500656u * 4);
    unsigned int*   temp      = (unsigned int*)  y1r;  // temp dead before gemm1
    unsigned short* h2b       = (unsigned short*)z;    // z dead after gemm1
    float*          z2        = y1r;                   // y1r dead after gemm2

    ginit_k<<<1, 256, 0, stream>>>(gcursor);
    bin_k<<<NTILE, 256, 0, stream>>>(edges, gcursor, temp);
    count_k<<<NBUCK, 256, 0, stream>>>(temp, gcursor, degi);

    prep_k<<<N_ENT * 64 / 256, 256, 0, stream>>>(entity_emb, degi, dinv, emb_b);

    scan_partials<<<NBLK_SCAN, 256, 0, stream>>>(degi, partials);
    scan_offsets<<<1, 512, 0, stream>>>(partials, row_start);
    scan_apply<<<NBLK_SCAN, 256, 0, stream>>>(degi, partials, row_start);

    unbin_k<<<NBUCK, 256, 0, stream>>>(temp, gcursor, row_start, srcs);

    reduce1_k<<<N_ENT * 64 / 256, 256, 0, stream>>>(row_start, srcs, emb_b, dinv, z);
    gemm1_relu<<<NBLK_G, 256, 0, stream>>>(z, W1, b1, y1r);
    gemm2_k<<<NBLK_G, 256, 0, stream>>>(y1r, W2, dinv, h2b);
    reduce2_k<<<N_ENT * 64 / 256, 256, 0, stream>>>(row_start, srcs, h2b, dinv, b2, z2);

    final_dot<<<BATCH * 64 / 256, 256, 0, stream>>>(u, iidx, user_emb, z2, out);
}

// Round 10
// 306.179 us; speedup vs baseline: 2.0051x; 1.1863x over previous
//
#include <hip/hip_runtime.h>
#include <hip/hip_bf16.h>
#include <math.h>

// Problem constants (from reference)
constexpr int N_ENT = 100000;
constexpr int NEDGE = 1600000;
constexpr int BATCH = 8192;
constexpr int NBLK_SCAN = (N_ENT + 255) / 256;   // 391

// Bucketed CSR placement
constexpr int NBUCK   = 256;
constexpr int KNODE   = 391;                      // 256*391 >= N_ENT
constexpr int TILE    = 4096;
constexpr int NTILE   = (NEDGE + TILE - 1) / TILE; // 391
constexpr int BUCKCAP = 8192;                     // fixed bucket region

constexpr int NBLK_G = (N_ENT + 63) / 64;         // 1563 (64-row GEMM tiles)

// bf16 helpers (RNE pack, exact unpack)
__device__ inline unsigned short f2b(float x) {
    unsigned int u = __float_as_uint(x);
    unsigned int r = (u + 0x7fffu + ((u >> 16) & 1u)) >> 16;
    return (unsigned short)r;
}
__device__ inline float b2f(unsigned short h) {
    return __uint_as_float(((unsigned int)h) << 16);
}

// ---------------------------------------------------------------------------
// Workspace layout (4-byte units): same as R9.
//  degi[0,100000) dinv[100000,200000) row_start[200000,300001)
//  gcursor[300004,300260) partials[300264,300655) srcs[300656,1900656)
//  emb_b(ushort)[1900656,5100656) z/h2b[5100656,11500656)
//  y1r/temp[11500656,24300656)

// K1: prep — dinv + premultiplied bf16 entity rows
__global__ __launch_bounds__(256) void prep_k(const float* __restrict__ emb,
                                              const int* __restrict__ degi,
                                              float* __restrict__ dinv,
                                              unsigned short* __restrict__ emb_b) {
    int gt   = blockIdx.x * 256 + threadIdx.x;
    int n    = gt >> 6;
    int lane = threadIdx.x & 63;
    float v = emb[(size_t)n * 64 + lane];
    float s = v * v;
#pragma unroll
    for (int o = 32; o > 0; o >>= 1) s += __shfl_xor(s, o, 64);
    float nrm = sqrtf(s);
    float sc  = nrm > 1.0f ? 1.0f / nrm : 1.0f;
    float dv  = 1.0f / sqrtf((float)(degi[n] + 1));
    if (lane == 0) dinv[n] = dv;
    emb_b[(size_t)n * 64 + lane] = f2b(sc * dv * v);
}

// K0a: gcursor init to fixed bucket bases
__global__ __launch_bounds__(256) void ginit_k(int* __restrict__ gcursor) {
    gcursor[threadIdx.x] = threadIdx.x * BUCKCAP;
}

// K0b: bucket binning into fixed-capacity regions
__global__ __launch_bounds__(256) void bin_k(const int* __restrict__ edges,
                                             int* __restrict__ gcursor,
                                             unsigned int* __restrict__ temp) {
    __shared__ int cnt[NBUCK];
    __shared__ int gb[NBUCK];
    __shared__ int off[NBUCK];
    int tid  = threadIdx.x;
    int base = blockIdx.x * TILE;
    int sv[16], dv[16], bv[16];
    cnt[tid] = 0;
    __syncthreads();
#pragma unroll
    for (int i = 0; i < 16; ++i) {
        int e = base + i * 256 + tid;
        if (e < NEDGE) {
            sv[i] = edges[e];
            dv[i] = edges[NEDGE + e];
            bv[i] = dv[i] / KNODE;
            atomicAdd(&cnt[bv[i]], 1);
        } else {
            bv[i] = -1;
        }
    }
    __syncthreads();
    if (cnt[tid] > 0) gb[tid] = atomicAdd(&gcursor[tid], cnt[tid]);
    off[tid] = 0;
    __syncthreads();
#pragma unroll
    for (int i = 0; i < 16; ++i) {
        int b = bv[i];
        if (b >= 0) {
            int p  = atomicAdd(&off[b], 1);
            int dl = dv[i] - b * KNODE;
            temp[gb[b] + p] = ((unsigned int)sv[i] << 9) | (unsigned int)dl;
        }
    }
}

// K0c: per-bucket degree histogram from binned temp
__global__ __launch_bounds__(256) void count_k(const unsigned int* __restrict__ temp,
                                               const int* __restrict__ gcursor,
                                               int* __restrict__ degi) {
    __shared__ int cnt[KNODE];
    int b     = blockIdx.x;
    int node0 = b * KNODE;
    int nn    = N_ENT - node0; if (nn > KNODE) nn = KNODE;
    for (int i = threadIdx.x; i < KNODE; i += 256) cnt[i] = 0;
    __syncthreads();
    int tbeg = b * BUCKCAP;
    int tend = gcursor[b];
    for (int idx = tbeg + threadIdx.x; idx < tend; idx += 256)
        atomicAdd(&cnt[temp[idx] & 511u], 1);
    __syncthreads();
    for (int i = threadIdx.x; i < nn; i += 256) degi[node0 + i] = cnt[i];
}

// K3a/b/c: hierarchical exclusive scan of degi -> row_start
__global__ __launch_bounds__(256) void scan_partials(const int* __restrict__ degi,
                                                     int* __restrict__ partials) {
    __shared__ int ws[4];
    int i = blockIdx.x * 256 + threadIdx.x;
    int v = (i < N_ENT) ? degi[i] : 0;
#pragma unroll
    for (int o = 32; o > 0; o >>= 1) v += __shfl_xor(v, o, 64);
    if ((threadIdx.x & 63) == 0) ws[threadIdx.x >> 6] = v;
    __syncthreads();
    if (threadIdx.x == 0) partials[blockIdx.x] = ws[0] + ws[1] + ws[2] + ws[3];
}

__global__ __launch_bounds__(512) void scan_offsets(int* __restrict__ partials,
                                                    int* __restrict__ row_start) {
    __shared__ int ts[512];
    int t = threadIdx.x;
    int v = (t < NBLK_SCAN) ? partials[t] : 0;
    ts[t] = v;
    __syncthreads();
    for (int off = 1; off < 512; off <<= 1) {
        int x = (t >= off) ? ts[t - off] : 0;
        __syncthreads();
        ts[t] += x;
        __syncthreads();
    }
    if (t < NBLK_SCAN) partials[t] = ts[t] - v;
    if (t == 0) row_start[N_ENT] = NEDGE;
}

__global__ __launch_bounds__(256) void scan_apply(const int* __restrict__ degi,
                                                  const int* __restrict__ partials,
                                                  int* __restrict__ row_start) {
    __shared__ int ts[256];
    int t = threadIdx.x;
    int i = blockIdx.x * 256 + t;
    int v = (i < N_ENT) ? degi[i] : 0;
    ts[t] = v;
    __syncthreads();
    for (int off = 1; off < 256; off <<= 1) {
        int x = (t >= off) ? ts[t - off] : 0;
        __syncthreads();
        ts[t] += x;
        __syncthreads();
    }
    if (i < N_ENT) row_start[i] = ts[t] - v + partials[blockIdx.x];
}

// K4b: within-bucket placement
__global__ __launch_bounds__(256) void unbin_k(const unsigned int* __restrict__ temp,
                                               const int* __restrict__ gcursor,
                                               const int* __restrict__ row_start,
                                               int* __restrict__ srcs) {
    __shared__ int cur[KNODE];
    int b     = blockIdx.x;
    int node0 = b * KNODE;
    int nn    = N_ENT - node0; if (nn > KNODE) nn = KNODE;
    for (int i = threadIdx.x; i < nn; i += 256) cur[i] = row_start[node0 + i];
    __syncthreads();
    int tbeg = b * BUCKCAP;
    int tend = gcursor[b];
    for (int idx = tbeg + threadIdx.x; idx < tend; idx += 256) {
        unsigned int v = temp[idx];
        int dl = (int)(v & 511u);
        int s  = (int)(v >> 9);
        int pos = atomicAdd(&cur[dl], 1);
        srcs[pos] = s;
    }
}

// K5: layer-1 aggregate: z[d] = dinv[d] * (sum_j emb_b[s_j] + emb_b[d])
__global__ __launch_bounds__(256) void reduce1_k(const int* __restrict__ row_start,
                                                 const int* __restrict__ srcs,
                                                 const unsigned short* __restrict__ emb_b,
                                                 const float* __restrict__ dinv,
                                                 float* __restrict__ z) {
    int gt   = blockIdx.x * 256 + threadIdx.x;
    int dst  = gt >> 6;
    int lane = threadIdx.x & 63;
    int beg = row_start[dst];
    int end = row_start[dst + 1];
    float a0 = 0.f, a1 = 0.f, a2 = 0.f, a3 = 0.f;
    for (int base = beg; base < end; base += 64) {
        int cnt = end - base; if (cnt > 64) cnt = 64;
        int s_v = (base + lane < end) ? srcs[base + lane] : 0;
        int jj = 0;
        for (; jj + 3 < cnt; jj += 4) {
            int s0 = __shfl(s_v, jj, 64),     s1 = __shfl(s_v, jj + 1, 64);
            int s2 = __shfl(s_v, jj + 2, 64), s3 = __shfl(s_v, jj + 3, 64);
            a0 += b2f(emb_b[(size_t)s0 * 64 + lane]);
            a1 += b2f(emb_b[(size_t)s1 * 64 + lane]);
            a2 += b2f(emb_b[(size_t)s2 * 64 + lane]);
            a3 += b2f(emb_b[(size_t)s3 * 64 + lane]);
        }
        for (; jj < cnt; ++jj) {
            int s0 = __shfl(s_v, jj, 64);
            a0 += b2f(emb_b[(size_t)s0 * 64 + lane]);
        }
    }
    float own = b2f(emb_b[(size_t)dst * 64 + lane]);
    z[(size_t)dst * 64 + lane] = dinv[dst] * (a0 + a1 + a2 + a3 + own);
}

// K6: y1r = relu(z @ W1 + b1)  [N,64]@[64,128] — register-blocked 8x4/thread.
__global__ __launch_bounds__(256) void gemm1_relu(const float* __restrict__ z,
                                                  const float* __restrict__ W1g,
                                                  const float* __restrict__ b1,
                                                  float* __restrict__ y1r) {
    __shared__ float As[64 * 68];
    __shared__ float Ws[64 * 132];
    int tid  = threadIdx.x;
    int row0 = blockIdx.x * 64;
    for (int idx = tid; idx < 1024; idx += 256) {
        int r = idx >> 4, c4 = (idx & 15) * 4;
        int grow = row0 + r;
        float4 v = make_float4(0.f, 0.f, 0.f, 0.f);
        if (grow < N_ENT) v = *(const float4*)(z + (size_t)grow * 64 + c4);
        *(float4*)(As + r * 68 + c4) = v;
    }
    for (int idx = tid; idx < 2048; idx += 256) {
        int k = idx >> 5, c4 = (idx & 31) * 4;
        *(float4*)(Ws + k * 132 + c4) = *(const float4*)(W1g + k * 128 + c4);
    }
    __syncthreads();

    int cg = tid & 31;
    int rg = tid >> 5;
    int c0 = cg * 4;
    int r0 = rg * 8;
    const float4* A4 = (const float4*)As;   // row stride 17
    const float4* W4 = (const float4*)Ws;   // row stride 33
    float acc[8][4];
#pragma unroll
    for (int i = 0; i < 8; ++i)
#pragma unroll
        for (int j = 0; j < 4; ++j) acc[i][j] = 0.f;

    for (int k4 = 0; k4 < 16; ++k4) {
        float4 w0 = W4[(4 * k4 + 0) * 33 + cg];
        float4 w1 = W4[(4 * k4 + 1) * 33 + cg];
        float4 w2 = W4[(4 * k4 + 2) * 33 + cg];
        float4 w3 = W4[(4 * k4 + 3) * 33 + cg];
#pragma unroll
        for (int i = 0; i < 8; ++i) {
            float4 a = A4[(r0 + i) * 17 + k4];
            acc[i][0] += a.x * w0.x + a.y * w1.x + a.z * w2.x + a.w * w3.x;
            acc[i][1] += a.x * w0.y + a.y * w1.y + a.z * w2.y + a.w * w3.y;
            acc[i][2] += a.x * w0.z + a.y * w1.z + a.z * w2.z + a.w * w3.z;
            acc[i][3] += a.x * w0.w + a.y * w1.w + a.z * w2.w + a.w * w3.w;
        }
    }
    float4 bb = *(const float4*)(b1 + c0);
#pragma unroll
    for (int i = 0; i < 8; ++i) {
        int grow = row0 + r0 + i;
        if (grow < N_ENT) {
            float4 o;
            o.x = fmaxf(acc[i][0] + bb.x, 0.f);
            o.y = fmaxf(acc[i][1] + bb.y, 0.f);
            o.z = fmaxf(acc[i][2] + bb.z, 0.f);
            o.w = fmaxf(acc[i][3] + bb.w, 0.f);
            *(float4*)(y1r + (size_t)grow * 128 + c0) = o;
        }
    }
}

// K7: h2b = bf16(dinv[row]*(y1r @ W2))  [N,128]@[128,64] — 4x4/thread.
__global__ __launch_bounds__(256) void gemm2_k(const float* __restrict__ y1r,
                                               const float* __restrict__ W2g,
                                               const float* __restrict__ dinv,
                                               unsigned short* __restrict__ h2b) {
    __shared__ float Ys[64 * 132];
    __shared__ float Ws[128 * 68];
    int tid  = threadIdx.x;
    int row0 = blockIdx.x * 64;
    for (int idx = tid; idx < 2048; idx += 256) {
        int r = idx >> 5, c4 = (idx & 31) * 4;
        int grow = row0 + r;
        float4 v = make_float4(0.f, 0.f, 0.f, 0.f);
        if (grow < N_ENT) v = *(const float4*)(y1r + (size_t)grow * 128 + c4);
        *(float4*)(Ys + r * 132 + c4) = v;
    }
    for (int idx = tid; idx < 2048; idx += 256) {
        int k = idx >> 4, c4 = (idx & 15) * 4;
        *(float4*)(Ws + k * 68 + c4) = *(const float4*)(W2g + k * 64 + c4);
    }
    __syncthreads();

    int cg = tid & 15;
    int rg = tid >> 4;
    int c0 = cg * 4;
    int r0 = rg * 4;
    const float4* Y4 = (const float4*)Ys;   // row stride 33
    const float4* W4 = (const float4*)Ws;   // row stride 17
    float acc[4][4];
#pragma unroll
    for (int i = 0; i < 4; ++i)
#pragma unroll
        for (int j = 0; j < 4; ++j) acc[i][j] = 0.f;

    for (int k4 = 0; k4 < 32; ++k4) {
        float4 w0 = W4[(4 * k4 + 0) * 17 + cg];
        float4 w1 = W4[(4 * k4 + 1) * 17 + cg];
        float4 w2 = W4[(4 * k4 + 2) * 17 + cg];
        float4 w3 = W4[(4 * k4 + 3) * 17 + cg];
#pragma unroll
        for (int i = 0; i < 4; ++i) {
            float4 a = Y4[(r0 + i) * 33 + k4];
            acc[i][0] += a.x * w0.x + a.y * w1.x + a.z * w2.x + a.w * w3.x;
            acc[i][1] += a.x * w0.y + a.y * w1.y + a.z * w2.y + a.w * w3.y;
            acc[i][2] += a.x * w0.z + a.y * w1.z + a.z * w2.z + a.w * w3.z;
            acc[i][3] += a.x * w0.w + a.y * w1.w + a.z * w2.w + a.w * w3.w;
        }
    }
#pragma unroll
    for (int i = 0; i < 4; ++i) {
        int grow = row0 + r0 + i;
        if (grow < N_ENT) {
            float dv = dinv[grow];
            unsigned int h0 = f2b(acc[i][0] * dv);
            unsigned int h1 = f2b(acc[i][1] * dv);
            unsigned int h2 = f2b(acc[i][2] * dv);
            unsigned int h3 = f2b(acc[i][3] * dv);
            uint2 p;
            p.x = h0 | (h1 << 16);
            p.y = h2 | (h3 << 16);
            *(uint2*)(h2b + (size_t)grow * 64 + c0) = p;
        }
    }
}

// K8: fused layer-2 aggregate + final dot — ONLY for the 8192 batch items
// (z2 was computed for all 100k nodes but final_dot reads just x[i]: 12x
// less gather work; z2 never materialized).
// z2row = dinv[d]*(sum_j h2b[s_j] + h2b[d]) + b2;  out = sigmoid(renorm(u)·z2row)
__global__ __launch_bounds__(256) void reduce2f_k(const int* __restrict__ u,
                                                  const int* __restrict__ iidx,
                                                  const float* __restrict__ uemb,
                                                  const int* __restrict__ row_start,
                                                  const int* __restrict__ srcs,
                                                  const unsigned short* __restrict__ h2b,
                                                  const float* __restrict__ dinv,
                                                  const float* __restrict__ b2,
                                                  float* __restrict__ out) {
    int gt   = blockIdx.x * 256 + threadIdx.x;
    int b    = gt >> 6;
    int lane = threadIdx.x & 63;
    int dst = iidx[b];
    int beg = row_start[dst];
    int end = row_start[dst + 1];
    float a0 = 0.f, a1 = 0.f, a2 = 0.f, a3 = 0.f;
    for (int base = beg; base < end; base += 64) {
        int cnt = end - base; if (cnt > 64) cnt = 64;
        int s_v = (base + lane < end) ? srcs[base + lane] : 0;
        int jj = 0;
        for (; jj + 3 < cnt; jj += 4) {
            int s0 = __shfl(s_v, jj, 64),     s1 = __shfl(s_v, jj + 1, 64);
            int s2 = __shfl(s_v, jj + 2, 64), s3 = __shfl(s_v, jj + 3, 64);
            a0 += b2f(h2b[(size_t)s0 * 64 + lane]);
            a1 += b2f(h2b[(size_t)s1 * 64 + lane]);
            a2 += b2f(h2b[(size_t)s2 * 64 + lane]);
            a3 += b2f(h2b[(size_t)s3 * 64 + lane]);
        }
        for (; jj < cnt; ++jj) {
            int s0 = __shfl(s_v, jj, 64);
            a0 += b2f(h2b[(size_t)s0 * 64 + lane]);
        }
    }
    float own  = b2f(h2b[(size_t)dst * 64 + lane]);
    float z2v  = dinv[dst] * (a0 + a1 + a2 + a3 + own) + b2[lane];
    float ue   = uemb[(size_t)u[b] * 64 + lane];
    float s1 = ue * ue;
    float s2 = ue * z2v;
#pragma unroll
    for (int o = 32; o > 0; o >>= 1) {
        s1 += __shfl_xor(s1, o, 64);
        s2 += __shfl_xor(s2, o, 64);
    }
    if (lane == 0) {
        float nrm = sqrtf(s1);
        float sc  = nrm > 1.0f ? 1.0f / nrm : 1.0f;
        float uv  = s2 * sc;
        out[b] = 1.0f / (1.0f + expf(-uv));
    }
}

// ---------------------------------------------------------------------------
extern "C" void kernel_launch(void* const* d_in, const int* in_sizes, int n_in,
                              void* d_out, int out_size, void* d_ws, size_t ws_size,
                              hipStream_t stream) {
    const int*   u          = (const int*)d_in[0];
    const int*   iidx       = (const int*)d_in[1];
    const int*   edges      = (const int*)d_in[2];
    const float* user_emb   = (const float*)d_in[3];
    const float* entity_emb = (const float*)d_in[4];
    const float* W1         = (const float*)d_in[5];
    const float* b1         = (const float*)d_in[6];
    const float* W2         = (const float*)d_in[7];
    const float* b2         = (const float*)d_in[8];
    float*       out        = (float*)d_out;

    char* ws = (char*)d_ws;
    int*            degi      = (int*)           (ws);
    float*          dinv      = (float*)         (ws + 100000u * 4);
    int*            row_start = (int*)           (ws + 200000u * 4);
    int*            gcursor   = (int*)           (ws + 300004u * 4);
    int*            partials  = (int*)           (ws + 300264u * 4);
    int*            srcs      = (int*)           (ws + 300656u * 4);
    unsigned short* emb_b     = (unsigned short*)(ws + 1900656u * 4);
    float*          z         = (float*)         (ws + 5100656u * 4);
    float*          y1r       = (float*)         (ws + 11500656u * 4);
    unsigned int*   temp      = (unsigned int*)  y1r;  // temp dead before gemm1
    unsigned short* h2b       = (unsigned short*)z;    // z dead after gemm1

    ginit_k<<<1, 256, 0, stream>>>(gcursor);
    bin_k<<<NTILE, 256, 0, stream>>>(edges, gcursor, temp);
    count_k<<<NBUCK, 256, 0, stream>>>(temp, gcursor, degi);

    prep_k<<<N_ENT * 64 / 256, 256, 0, stream>>>(entity_emb, degi, dinv, emb_b);

    scan_partials<<<NBLK_SCAN, 256, 0, stream>>>(degi, partials);
    scan_offsets<<<1, 512, 0, stream>>>(partials, row_start);
    scan_apply<<<NBLK_SCAN, 256, 0, stream>>>(degi, partials, row_start);

    unbin_k<<<NBUCK, 256, 0, stream>>>(temp, gcursor, row_start, srcs);

    reduce1_k<<<N_ENT * 64 / 256, 256, 0, stream>>>(row_start, srcs, emb_b, dinv, z);
    gemm1_relu<<<NBLK_G, 256, 0, stream>>>(z, W1, b1, y1r);
    gemm2_k<<<NBLK_G, 256, 0, stream>>>(y1r, W2, dinv, h2b);

    reduce2f_k<<<BATCH * 64 / 256, 256, 0, stream>>>(u, iidx, user_emb, row_start,
                                                     srcs, h2b, dinv, b2, out);
}

// Round 11
// 300.834 us; speedup vs baseline: 2.0407x; 1.0178x over previous
//
#include <hip/hip_runtime.h>
#include <hip/hip_bf16.h>
#include <math.h>

// Problem constants (from reference)
constexpr int N_ENT = 100000;
constexpr int NEDGE = 1600000;
constexpr int BATCH = 8192;
constexpr int NBLK_SCAN = (N_ENT + 255) / 256;   // 391

// Bucketed CSR placement
constexpr int NBUCK   = 256;
constexpr int KNODE   = 391;                      // 256*391 >= N_ENT
constexpr int TILE    = 4096;
constexpr int NTILE   = (NEDGE + TILE - 1) / TILE; // 391
constexpr int BUCKCAP = 8192;                     // fixed bucket region

constexpr int NBLK_G = (N_ENT + 63) / 64;         // 1563 (64-row GEMM tiles)

// bf16 helpers (RNE pack, exact unpack)
__device__ inline unsigned short f2b(float x) {
    unsigned int u = __float_as_uint(x);
    unsigned int r = (u + 0x7fffu + ((u >> 16) & 1u)) >> 16;
    return (unsigned short)r;
}
__device__ inline float b2f(unsigned short h) {
    return __uint_as_float(((unsigned int)h) << 16);
}
__device__ inline float blo(unsigned int p) { return __uint_as_float(p << 16); }
__device__ inline float bhi(unsigned int p) { return __uint_as_float(p & 0xffff0000u); }

// ---------------------------------------------------------------------------
// Workspace layout (4-byte units):
//  degi      : [0, 100000)
//  dinv      : [100000, 200000)
//  row_start : [200000, 300001)
//  gcursor   : [300004, 300260)
//  partials  : [300264, 300655)
//  srcs      : [300656, 1900656)
//  emb_b     : [1900656, 5100688)   ushort[(N+1)*64] (+ zero row)
//  z / h2b   : [5100688, 11500688)  float [N,64]; h2b (ushort[(N+1)*64]) reuses
//  y1r/temp  : [11500688, 24300688) float [N,128]; temp overlaps (dead until gemm1)

// K1: prep — dinv + premultiplied bf16 entity rows (+ zero row at N_ENT)
__global__ __launch_bounds__(256) void prep_k(const float* __restrict__ emb,
                                              const int* __restrict__ degi,
                                              float* __restrict__ dinv,
                                              unsigned short* __restrict__ emb_b) {
    int gt   = blockIdx.x * 256 + threadIdx.x;
    int n    = gt >> 6;
    int lane = threadIdx.x & 63;
    if (n > N_ENT) return;
    if (n == N_ENT) { emb_b[(size_t)n * 64 + lane] = 0; return; }
    float v = emb[(size_t)n * 64 + lane];
    float s = v * v;
#pragma unroll
    for (int o = 32; o > 0; o >>= 1) s += __shfl_xor(s, o, 64);
    float nrm = sqrtf(s);
    float sc  = nrm > 1.0f ? 1.0f / nrm : 1.0f;
    float dv  = 1.0f / sqrtf((float)(degi[n] + 1));
    if (lane == 0) dinv[n] = dv;
    emb_b[(size_t)n * 64 + lane] = f2b(sc * dv * v);
}

// K0a: gcursor init to fixed bucket bases
__global__ __launch_bounds__(256) void ginit_k(int* __restrict__ gcursor) {
    gcursor[threadIdx.x] = threadIdx.x * BUCKCAP;
}

// K0b: bucket binning into fixed-capacity regions
__global__ __launch_bounds__(256) void bin_k(const int* __restrict__ edges,
                                             int* __restrict__ gcursor,
                                             unsigned int* __restrict__ temp) {
    __shared__ int cnt[NBUCK];
    __shared__ int gb[NBUCK];
    __shared__ int off[NBUCK];
    int tid  = threadIdx.x;
    int base = blockIdx.x * TILE;
    int sv[16], dv[16], bv[16];
    cnt[tid] = 0;
    __syncthreads();
#pragma unroll
    for (int i = 0; i < 16; ++i) {
        int e = base + i * 256 + tid;
        if (e < NEDGE) {
            sv[i] = edges[e];
            dv[i] = edges[NEDGE + e];
            bv[i] = dv[i] / KNODE;
            atomicAdd(&cnt[bv[i]], 1);
        } else {
            bv[i] = -1;
        }
    }
    __syncthreads();
    if (cnt[tid] > 0) gb[tid] = atomicAdd(&gcursor[tid], cnt[tid]);
    off[tid] = 0;
    __syncthreads();
#pragma unroll
    for (int i = 0; i < 16; ++i) {
        int b = bv[i];
        if (b >= 0) {
            int p  = atomicAdd(&off[b], 1);
            int dl = dv[i] - b * KNODE;
            temp[gb[b] + p] = ((unsigned int)sv[i] << 9) | (unsigned int)dl;
        }
    }
}

// K0c: per-bucket degree histogram from binned temp
__global__ __launch_bounds__(256) void count_k(const unsigned int* __restrict__ temp,
                                               const int* __restrict__ gcursor,
                                               int* __restrict__ degi) {
    __shared__ int cnt[KNODE];
    int b     = blockIdx.x;
    int node0 = b * KNODE;
    int nn    = N_ENT - node0; if (nn > KNODE) nn = KNODE;
    for (int i = threadIdx.x; i < KNODE; i += 256) cnt[i] = 0;
    __syncthreads();
    int tbeg = b * BUCKCAP;
    int tend = gcursor[b];
    for (int idx = tbeg + threadIdx.x; idx < tend; idx += 256)
        atomicAdd(&cnt[temp[idx] & 511u], 1);
    __syncthreads();
    for (int i = threadIdx.x; i < nn; i += 256) degi[node0 + i] = cnt[i];
}

// K3a/b/c: hierarchical exclusive scan of degi -> row_start
__global__ __launch_bounds__(256) void scan_partials(const int* __restrict__ degi,
                                                     int* __restrict__ partials) {
    __shared__ int ws[4];
    int i = blockIdx.x * 256 + threadIdx.x;
    int v = (i < N_ENT) ? degi[i] : 0;
#pragma unroll
    for (int o = 32; o > 0; o >>= 1) v += __shfl_xor(v, o, 64);
    if ((threadIdx.x & 63) == 0) ws[threadIdx.x >> 6] = v;
    __syncthreads();
    if (threadIdx.x == 0) partials[blockIdx.x] = ws[0] + ws[1] + ws[2] + ws[3];
}

__global__ __launch_bounds__(512) void scan_offsets(int* __restrict__ partials,
                                                    int* __restrict__ row_start) {
    __shared__ int ts[512];
    int t = threadIdx.x;
    int v = (t < NBLK_SCAN) ? partials[t] : 0;
    ts[t] = v;
    __syncthreads();
    for (int off = 1; off < 512; off <<= 1) {
        int x = (t >= off) ? ts[t - off] : 0;
        __syncthreads();
        ts[t] += x;
        __syncthreads();
    }
    if (t < NBLK_SCAN) partials[t] = ts[t] - v;
    if (t == 0) row_start[N_ENT] = NEDGE;
}

__global__ __launch_bounds__(256) void scan_apply(const int* __restrict__ degi,
                                                  const int* __restrict__ partials,
                                                  int* __restrict__ row_start) {
    __shared__ int ts[256];
    int t = threadIdx.x;
    int i = blockIdx.x * 256 + t;
    int v = (i < N_ENT) ? degi[i] : 0;
    ts[t] = v;
    __syncthreads();
    for (int off = 1; off < 256; off <<= 1) {
        int x = (t >= off) ? ts[t - off] : 0;
        __syncthreads();
        ts[t] += x;
        __syncthreads();
    }
    if (i < N_ENT) row_start[i] = ts[t] - v + partials[blockIdx.x];
}

// K4b: within-bucket placement
__global__ __launch_bounds__(256) void unbin_k(const unsigned int* __restrict__ temp,
                                               const int* __restrict__ gcursor,
                                               const int* __restrict__ row_start,
                                               int* __restrict__ srcs) {
    __shared__ int cur[KNODE];
    int b     = blockIdx.x;
    int node0 = b * KNODE;
    int nn    = N_ENT - node0; if (nn > KNODE) nn = KNODE;
    for (int i = threadIdx.x; i < nn; i += 256) cur[i] = row_start[node0 + i];
    __syncthreads();
    int tbeg = b * BUCKCAP;
    int tend = gcursor[b];
    for (int idx = tbeg + threadIdx.x; idx < tend; idx += 256) {
        unsigned int v = temp[idx];
        int dl = (int)(v & 511u);
        int s  = (int)(v >> 9);
        int pos = atomicAdd(&cur[dl], 1);
        srcs[pos] = s;
    }
}

// K5: layer-1 aggregate, 4 edges per gather instruction.
// Lane = (edge-slot sub = lane>>4, col-group li = lane&15); each lane loads
// uint2 = 4 bf16 cols of its slot's src row. OOB slots hit the zero row at
// N_ENT (no masking in hot loop). z[d] = dinv[d]*(sum emb_b[s_j] + emb_b[d]).
__global__ __launch_bounds__(256) void reduce1_k(const int* __restrict__ row_start,
                                                 const int* __restrict__ srcs,
                                                 const unsigned short* __restrict__ emb_b,
                                                 const float* __restrict__ dinv,
                                                 float* __restrict__ z) {
    int gt   = blockIdx.x * 256 + threadIdx.x;
    int dst  = gt >> 6;
    int lane = threadIdx.x & 63;
    int sub  = lane >> 4;
    int li   = lane & 15;
    int beg = row_start[dst];
    int end = row_start[dst + 1];
    float4 acc = make_float4(0.f, 0.f, 0.f, 0.f);
    for (int base = beg; base < end; base += 64) {
        int cnt = end - base; if (cnt > 64) cnt = 64;
        int s_v = (base + lane < end) ? srcs[base + lane] : N_ENT;
        for (int jj = 0; jj < cnt; jj += 16) {
            int s0 = __shfl(s_v, jj + sub,      64);
            int s1 = __shfl(s_v, jj + 4 + sub,  64);
            int s2 = __shfl(s_v, jj + 8 + sub,  64);
            int s3 = __shfl(s_v, jj + 12 + sub, 64);
            uint2 p0 = *(const uint2*)(emb_b + (size_t)s0 * 64 + li * 4);
            uint2 p1 = *(const uint2*)(emb_b + (size_t)s1 * 64 + li * 4);
            uint2 p2 = *(const uint2*)(emb_b + (size_t)s2 * 64 + li * 4);
            uint2 p3 = *(const uint2*)(emb_b + (size_t)s3 * 64 + li * 4);
            acc.x += blo(p0.x) + blo(p1.x) + blo(p2.x) + blo(p3.x);
            acc.y += bhi(p0.x) + bhi(p1.x) + bhi(p2.x) + bhi(p3.x);
            acc.z += blo(p0.y) + blo(p1.y) + blo(p2.y) + blo(p3.y);
            acc.w += bhi(p0.y) + bhi(p1.y) + bhi(p2.y) + bhi(p3.y);
        }
    }
    // sum the 4 edge-slots
    acc.x += __shfl_xor(acc.x, 16, 64); acc.y += __shfl_xor(acc.y, 16, 64);
    acc.z += __shfl_xor(acc.z, 16, 64); acc.w += __shfl_xor(acc.w, 16, 64);
    acc.x += __shfl_xor(acc.x, 32, 64); acc.y += __shfl_xor(acc.y, 32, 64);
    acc.z += __shfl_xor(acc.z, 32, 64); acc.w += __shfl_xor(acc.w, 32, 64);
    if (lane < 16) {
        uint2 po = *(const uint2*)(emb_b + (size_t)dst * 64 + li * 4);
        float dv = dinv[dst];
        float4 o;
        o.x = dv * (acc.x + blo(po.x));
        o.y = dv * (acc.y + bhi(po.x));
        o.z = dv * (acc.z + blo(po.y));
        o.w = dv * (acc.w + bhi(po.y));
        *(float4*)(z + (size_t)dst * 64 + li * 4) = o;
    }
}

// K6: y1r = relu(z @ W1 + b1)  [N,64]@[64,128] — register-blocked 8x4/thread.
__global__ __launch_bounds__(256) void gemm1_relu(const float* __restrict__ z,
                                                  const float* __restrict__ W1g,
                                                  const float* __restrict__ b1,
                                                  float* __restrict__ y1r) {
    __shared__ float As[64 * 68];
    __shared__ float Ws[64 * 132];
    int tid  = threadIdx.x;
    int row0 = blockIdx.x * 64;
    for (int idx = tid; idx < 1024; idx += 256) {
        int r = idx >> 4, c4 = (idx & 15) * 4;
        int grow = row0 + r;
        float4 v = make_float4(0.f, 0.f, 0.f, 0.f);
        if (grow < N_ENT) v = *(const float4*)(z + (size_t)grow * 64 + c4);
        *(float4*)(As + r * 68 + c4) = v;
    }
    for (int idx = tid; idx < 2048; idx += 256) {
        int k = idx >> 5, c4 = (idx & 31) * 4;
        *(float4*)(Ws + k * 132 + c4) = *(const float4*)(W1g + k * 128 + c4);
    }
    __syncthreads();

    int cg = tid & 31;
    int rg = tid >> 5;
    int c0 = cg * 4;
    int r0 = rg * 8;
    const float4* A4 = (const float4*)As;   // row stride 17
    const float4* W4 = (const float4*)Ws;   // row stride 33
    float acc[8][4];
#pragma unroll
    for (int i = 0; i < 8; ++i)
#pragma unroll
        for (int j = 0; j < 4; ++j) acc[i][j] = 0.f;

    for (int k4 = 0; k4 < 16; ++k4) {
        float4 w0 = W4[(4 * k4 + 0) * 33 + cg];
        float4 w1 = W4[(4 * k4 + 1) * 33 + cg];
        float4 w2 = W4[(4 * k4 + 2) * 33 + cg];
        float4 w3 = W4[(4 * k4 + 3) * 33 + cg];
#pragma unroll
        for (int i = 0; i < 8; ++i) {
            float4 a = A4[(r0 + i) * 17 + k4];
            acc[i][0] += a.x * w0.x + a.y * w1.x + a.z * w2.x + a.w * w3.x;
            acc[i][1] += a.x * w0.y + a.y * w1.y + a.z * w2.y + a.w * w3.y;
            acc[i][2] += a.x * w0.z + a.y * w1.z + a.z * w2.z + a.w * w3.z;
            acc[i][3] += a.x * w0.w + a.y * w1.w + a.z * w2.w + a.w * w3.w;
        }
    }
    float4 bb = *(const float4*)(b1 + c0);
#pragma unroll
    for (int i = 0; i < 8; ++i) {
        int grow = row0 + r0 + i;
        if (grow < N_ENT) {
            float4 o;
            o.x = fmaxf(acc[i][0] + bb.x, 0.f);
            o.y = fmaxf(acc[i][1] + bb.y, 0.f);
            o.z = fmaxf(acc[i][2] + bb.z, 0.f);
            o.w = fmaxf(acc[i][3] + bb.w, 0.f);
            *(float4*)(y1r + (size_t)grow * 128 + c0) = o;
        }
    }
}

// K7: h2b = bf16(dinv[row]*(y1r @ W2))  [N,128]@[128,64] — 4x4/thread.
// Also writes the zero row at grow == N_ENT for reduce2f's OOB slots.
__global__ __launch_bounds__(256) void gemm2_k(const float* __restrict__ y1r,
                                               const float* __restrict__ W2g,
                                               const float* __restrict__ dinv,
                                               unsigned short* __restrict__ h2b) {
    __shared__ float Ys[64 * 132];
    __shared__ float Ws[128 * 68];
    int tid  = threadIdx.x;
    int row0 = blockIdx.x * 64;
    for (int idx = tid; idx < 2048; idx += 256) {
        int r = idx >> 5, c4 = (idx & 31) * 4;
        int grow = row0 + r;
        float4 v = make_float4(0.f, 0.f, 0.f, 0.f);
        if (grow < N_ENT) v = *(const float4*)(y1r + (size_t)grow * 128 + c4);
        *(float4*)(Ys + r * 132 + c4) = v;
    }
    for (int idx = tid; idx < 2048; idx += 256) {
        int k = idx >> 4, c4 = (idx & 15) * 4;
        *(float4*)(Ws + k * 68 + c4) = *(const float4*)(W2g + k * 64 + c4);
    }
    __syncthreads();

    int cg = tid & 15;
    int rg = tid >> 4;
    int c0 = cg * 4;
    int r0 = rg * 4;
    const float4* Y4 = (const float4*)Ys;   // row stride 33
    const float4* W4 = (const float4*)Ws;   // row stride 17
    float acc[4][4];
#pragma unroll
    for (int i = 0; i < 4; ++i)
#pragma unroll
        for (int j = 0; j < 4; ++j) acc[i][j] = 0.f;

    for (int k4 = 0; k4 < 32; ++k4) {
        float4 w0 = W4[(4 * k4 + 0) * 17 + cg];
        float4 w1 = W4[(4 * k4 + 1) * 17 + cg];
        float4 w2 = W4[(4 * k4 + 2) * 17 + cg];
        float4 w3 = W4[(4 * k4 + 3) * 17 + cg];
#pragma unroll
        for (int i = 0; i < 4; ++i) {
            float4 a = Y4[(r0 + i) * 33 + k4];
            acc[i][0] += a.x * w0.x + a.y * w1.x + a.z * w2.x + a.w * w3.x;
            acc[i][1] += a.x * w0.y + a.y * w1.y + a.z * w2.y + a.w * w3.y;
            acc[i][2] += a.x * w0.z + a.y * w1.z + a.z * w2.z + a.w * w3.z;
            acc[i][3] += a.x * w0.w + a.y * w1.w + a.z * w2.w + a.w * w3.w;
        }
    }
#pragma unroll
    for (int i = 0; i < 4; ++i) {
        int grow = row0 + r0 + i;
        if (grow < N_ENT) {
            float dv = dinv[grow];
            unsigned int h0 = f2b(acc[i][0] * dv);
            unsigned int h1 = f2b(acc[i][1] * dv);
            unsigned int h2 = f2b(acc[i][2] * dv);
            unsigned int h3 = f2b(acc[i][3] * dv);
            uint2 p;
            p.x = h0 | (h1 << 16);
            p.y = h2 | (h3 << 16);
            *(uint2*)(h2b + (size_t)grow * 64 + c0) = p;
        } else if (grow == N_ENT) {
            uint2 p; p.x = 0u; p.y = 0u;
            *(uint2*)(h2b + (size_t)grow * 64 + c0) = p;
        }
    }
}

// K8: fused layer-2 aggregate + final dot for the 8192 batch items,
// 4 edges per gather instruction (same lane layout as reduce1_k).
__global__ __launch_bounds__(256) void reduce2f_k(const int* __restrict__ u,
                                                  const int* __restrict__ iidx,
                                                  const float* __restrict__ uemb,
                                                  const int* __restrict__ row_start,
                                                  const int* __restrict__ srcs,
                                                  const unsigned short* __restrict__ h2b,
                                                  const float* __restrict__ dinv,
                                                  const float* __restrict__ b2,
                                                  float* __restrict__ out) {
    int gt   = blockIdx.x * 256 + threadIdx.x;
    int b    = gt >> 6;
    int lane = threadIdx.x & 63;
    int sub  = lane >> 4;
    int li   = lane & 15;
    int dst = iidx[b];
    int beg = row_start[dst];
    int end = row_start[dst + 1];
    float4 acc = make_float4(0.f, 0.f, 0.f, 0.f);
    for (int base = beg; base < end; base += 64) {
        int cnt = end - base; if (cnt > 64) cnt = 64;
        int s_v = (base + lane < end) ? srcs[base + lane] : N_ENT;
        for (int jj = 0; jj < cnt; jj += 16) {
            int s0 = __shfl(s_v, jj + sub,      64);
            int s1 = __shfl(s_v, jj + 4 + sub,  64);
            int s2 = __shfl(s_v, jj + 8 + sub,  64);
            int s3 = __shfl(s_v, jj + 12 + sub, 64);
            uint2 p0 = *(const uint2*)(h2b + (size_t)s0 * 64 + li * 4);
            uint2 p1 = *(const uint2*)(h2b + (size_t)s1 * 64 + li * 4);
            uint2 p2 = *(const uint2*)(h2b + (size_t)s2 * 64 + li * 4);
            uint2 p3 = *(const uint2*)(h2b + (size_t)s3 * 64 + li * 4);
            acc.x += blo(p0.x) + blo(p1.x) + blo(p2.x) + blo(p3.x);
            acc.y += bhi(p0.x) + bhi(p1.x) + bhi(p2.x) + bhi(p3.x);
            acc.z += blo(p0.y) + blo(p1.y) + blo(p2.y) + blo(p3.y);
            acc.w += bhi(p0.y) + bhi(p1.y) + bhi(p2.y) + bhi(p3.y);
        }
    }
    acc.x += __shfl_xor(acc.x, 16, 64); acc.y += __shfl_xor(acc.y, 16, 64);
    acc.z += __shfl_xor(acc.z, 16, 64); acc.w += __shfl_xor(acc.w, 16, 64);
    acc.x += __shfl_xor(acc.x, 32, 64); acc.y += __shfl_xor(acc.y, 32, 64);
    acc.z += __shfl_xor(acc.z, 32, 64); acc.w += __shfl_xor(acc.w, 32, 64);
    float s1 = 0.f, s2 = 0.f;
    if (lane < 16) {
        uint2 po = *(const uint2*)(h2b + (size_t)dst * 64 + li * 4);
        float dv = dinv[dst];
        float4 bb = *(const float4*)(b2 + li * 4);
        float4 z2v;
        z2v.x = dv * (acc.x + blo(po.x)) + bb.x;
        z2v.y = dv * (acc.y + bhi(po.x)) + bb.y;
        z2v.z = dv * (acc.z + blo(po.y)) + bb.z;
        z2v.w = dv * (acc.w + bhi(po.y)) + bb.w;
        float4 ue = *(const float4*)(uemb + (size_t)u[b] * 64 + li * 4);
        s1 = ue.x * ue.x + ue.y * ue.y + ue.z * ue.z + ue.w * ue.w;
        s2 = ue.x * z2v.x + ue.y * z2v.y + ue.z * z2v.z + ue.w * z2v.w;
    }
#pragma unroll
    for (int o = 8; o > 0; o >>= 1) {
        s1 += __shfl_xor(s1, o, 64);
        s2 += __shfl_xor(s2, o, 64);
    }
    if (lane == 0) {
        float nrm = sqrtf(s1);
        float sc  = nrm > 1.0f ? 1.0f / nrm : 1.0f;
        float uv  = s2 * sc;
        out[b] = 1.0f / (1.0f + expf(-uv));
    }
}

// ---------------------------------------------------------------------------
extern "C" void kernel_launch(void* const* d_in, const int* in_sizes, int n_in,
                              void* d_out, int out_size, void* d_ws, size_t ws_size,
                              hipStream_t stream) {
    const int*   u          = (const int*)d_in[0];
    const int*   iidx       = (const int*)d_in[1];
    const int*   edges      = (const int*)d_in[2];
    const float* user_emb   = (const float*)d_in[3];
    const float* entity_emb = (const float*)d_in[4];
    const float* W1         = (const float*)d_in[5];
    const float* b1         = (const float*)d_in[6];
    const float* W2         = (const float*)d_in[7];
    const float* b2         = (const float*)d_in[8];
    float*       out        = (float*)d_out;

    char* ws = (char*)d_ws;
    int*            degi      = (int*)           (ws);
    float*          dinv      = (float*)         (ws + 100000u * 4);
    int*            row_start = (int*)           (ws + 200000u * 4);
    int*            gcursor   = (int*)           (ws + 300004u * 4);
    int*            partials  = (int*)           (ws + 300264u * 4);
    int*            srcs      = (int*)           (ws + 300656u * 4);
    unsigned short* emb_b     = (unsigned short*)(ws + 1900656u * 4);  // (N+1)*64
    float*          z         = (float*)         (ws + 5100688u * 4);
    float*          y1r       = (float*)         (ws + 11500688u * 4);
    unsigned int*   temp      = (unsigned int*)  y1r;  // temp dead before gemm1
    unsigned short* h2b       = (unsigned short*)z;    // z dead after gemm1 ((N+1)*64)

    ginit_k<<<1, 256, 0, stream>>>(gcursor);
    bin_k<<<NTILE, 256, 0, stream>>>(edges, gcursor, temp);
    count_k<<<NBUCK, 256, 0, stream>>>(temp, gcursor, degi);

    prep_k<<<N_ENT * 64 / 256 + 1, 256, 0, stream>>>(entity_emb, degi, dinv, emb_b);

    scan_partials<<<NBLK_SCAN, 256, 0, stream>>>(degi, partials);
    scan_offsets<<<1, 512, 0, stream>>>(partials, row_start);
    scan_apply<<<NBLK_SCAN, 256, 0, stream>>>(degi, partials, row_start);

    unbin_k<<<NBUCK, 256, 0, stream>>>(temp, gcursor, row_start, srcs);

    reduce1_k<<<N_ENT * 64 / 256, 256, 0, stream>>>(row_start, srcs, emb_b, dinv, z);
    gemm1_relu<<<NBLK_G, 256, 0, stream>>>(z, W1, b1, y1r);
    gemm2_k<<<NBLK_G, 256, 0, stream>>>(y1r, W2, dinv, h2b);

    reduce2f_k<<<BATCH * 64 / 256, 256, 0, stream>>>(u, iidx, user_emb, row_start,
                                                     srcs, h2b, dinv, b2, out);
}